// Round 9
// baseline (331.280 us; speedup 1.0000x reference)
//
#include <hip/hip_runtime.h>
#include <hip/hip_bf16.h>
#include <stdint.h>
#include <stddef.h>

#define S_LEN 2048
#define HID   3584
#define NH    28
#define NKV   4
#define HD    128
#define REP   7
#define KVD   512
#define NQKV  4608          // 3584 + 512 + 512
#define KSPLIT_LEN 1792     // 3584 / 2
// QK scale with log2(e) folded in: softmax uses exp2
#define QK_SCALE_L2E 0.12752462155f   // (1/sqrt(128)) * log2(e)

typedef unsigned short u16;
typedef short short8 __attribute__((ext_vector_type(8)));
typedef float f32x4 __attribute__((ext_vector_type(4)));

__device__ __forceinline__ u16 f2bf(float f) {
  union { float f; uint32_t u; } v; v.f = f;
  uint32_t r = v.u + 0x7fffu + ((v.u >> 16) & 1u);
  return (u16)(r >> 16);
}
__device__ __forceinline__ float bf2f(u16 u) {
  union { uint32_t u; float f; } v; v.u = ((uint32_t)u) << 16;
  return v.f;
}
__device__ __forceinline__ u16 nbf(float f) {  // native 1-op RNE cvt
  __hip_bfloat16 h = __float2bfloat16(f);
  return *reinterpret_cast<u16*>(&h);
}

#define GLL16(gp, lp) __builtin_amdgcn_global_load_lds( \
    (const __attribute__((address_space(1))) void*)(gp), \
    (__attribute__((address_space(3))) void*)(lp), 16, 0, 0)

// ---------------- f32 -> bf16 bulk convert (all 5 buffers, one launch) -------
__global__ __launch_bounds__(256) void cvt_all_kernel(
    const float* __restrict__ h, const float* __restrict__ qw,
    const float* __restrict__ kw, const float* __restrict__ vw,
    const float* __restrict__ ow,
    u16* __restrict__ hb, u16* __restrict__ qwb, u16* __restrict__ kwb,
    u16* __restrict__ vwb, u16* __restrict__ owb)
{
  const float* src; u16* dst; int n4;
  switch (blockIdx.y) {
    case 0: src = h;  dst = hb;  n4 = S_LEN * HID / 4; break;
    case 1: src = qw; dst = qwb; n4 = HID * HID / 4;   break;
    case 2: src = kw; dst = kwb; n4 = KVD * HID / 4;   break;
    case 3: src = vw; dst = vwb; n4 = KVD * HID / 4;   break;
    default: src = ow; dst = owb; n4 = HID * HID / 4;  break;
  }
  int i = blockIdx.x * blockDim.x + threadIdx.x;
  const int stride = gridDim.x * blockDim.x;
  for (; i < n4; i += stride) {
    float4 v = reinterpret_cast<const float4*>(src)[i];
    uint2 o;
    o.x = (uint32_t)f2bf(v.x) | ((uint32_t)f2bf(v.y) << 16);
    o.y = (uint32_t)f2bf(v.z) | ((uint32_t)f2bf(v.w) << 16);
    reinterpret_cast<uint2*>(dst)[i] = o;
  }
}

// ---- GEMM core: 128x256 tile, 8 waves (2Mx4N, wave=64x64), BK=64,
// triple-buffered LDS with counted vmcnt (loads stay in flight across
// barriers; vmcnt(6) steady-state, vmcnt(0) only on the last K-tile).
__device__ __forceinline__ void gemm_core_128x256(
    u16* lds, const u16* __restrict__ A, const u16* __restrict__ W,
    u16* __restrict__ C, int ldC, int lda, int T)
{
  const int t  = threadIdx.x;       // 0..511
  const int l  = t & 63;
  const int w  = t >> 6;            // 0..7
  const int lr = l & 15;
  const int lg = l >> 4;
  const int wm = (w >> 2) << 6;     // 0 or 64
  const int wn = (w & 3) << 6;      // 0,64,128,192
  const int sw = (lr & 7) << 3;

  const f32x4 fz = {0.f, 0.f, 0.f, 0.f};
  f32x4 acc[4][4];
#pragma unroll
  for (int i = 0; i < 4; ++i)
#pragma unroll
    for (int j = 0; j < 4; ++j) acc[i][j] = fz;

#define STAGE2(kt, buf) do {                                          \
    const u16* As_ = A + (size_t)(kt) * 64;                           \
    const u16* Ws_ = W + (size_t)(kt) * 64;                           \
    _Pragma("unroll")                                                 \
    for (int i_ = 0; i_ < 2; ++i_) {                                  \
      const int e_ = (i_ * 512 + t) * 8;                              \
      const int r_ = e_ >> 6;                                         \
      const int c_ = (e_ & 63) ^ ((r_ & 7) << 3);                     \
      GLL16(As_ + (size_t)r_ * lda + c_, (buf) + e_);                 \
    }                                                                 \
    _Pragma("unroll")                                                 \
    for (int i_ = 0; i_ < 4; ++i_) {                                  \
      const int e_ = (i_ * 512 + t) * 8;                              \
      const int r_ = e_ >> 6;                                         \
      const int c_ = (e_ & 63) ^ ((r_ & 7) << 3);                     \
      GLL16(Ws_ + (size_t)r_ * lda + c_, (buf) + 8192 + e_);          \
    }                                                                 \
  } while (0)

  STAGE2(0, lds);
  STAGE2(1, lds + 24576);

#pragma unroll 1
  for (int tk = 0; tk < T; ++tk) {
    if (tk + 1 < T) { asm volatile("s_waitcnt vmcnt(6)" ::: "memory"); }
    else            { asm volatile("s_waitcnt vmcnt(0)" ::: "memory"); }
    __builtin_amdgcn_sched_barrier(0);
    __builtin_amdgcn_s_barrier();
    __builtin_amdgcn_sched_barrier(0);

    if (tk + 2 < T) {
      u16* nb = lds + ((tk + 2) % 3) * 24576;
      STAGE2(tk + 2, nb);
    }

    const u16* As_ = lds + (tk % 3) * 24576;
    const u16* Bs_ = As_ + 8192;
#pragma unroll
    for (int kk = 0; kk < 2; ++kk) {
      short8 af[4], bfr[4];
#pragma unroll
      for (int mi = 0; mi < 4; ++mi)
        af[mi] = *(const short8*)(As_ + (wm + mi * 16 + lr) * 64 + ((kk * 32 + lg * 8) ^ sw));
#pragma unroll
      for (int ni = 0; ni < 4; ++ni)
        bfr[ni] = *(const short8*)(Bs_ + (wn + ni * 16 + lr) * 64 + ((kk * 32 + lg * 8) ^ sw));
      __builtin_amdgcn_s_setprio(1);
#pragma unroll
      for (int mi = 0; mi < 4; ++mi)
#pragma unroll
        for (int ni = 0; ni < 4; ++ni)
          acc[mi][ni] = __builtin_amdgcn_mfma_f32_16x16x32_bf16(af[mi], bfr[ni], acc[mi][ni], 0, 0, 0);
      __builtin_amdgcn_s_setprio(0);
    }
  }
#undef STAGE2

#pragma unroll
  for (int ni = 0; ni < 4; ++ni) {
    const int n = wn + ni * 16 + lr;
#pragma unroll
    for (int mi = 0; mi < 4; ++mi) {
#pragma unroll
      for (int r = 0; r < 4; ++r) {
        const int m = wm + mi * 16 + lg * 4 + r;
        C[(size_t)m * ldC + n] = f2bf(acc[mi][ni][r]);
      }
    }
  }
}

// QKV: partials [2][S][NQKV]; grid (16, 18, 2); XCD-chunk swizzle (288=8*36)
__global__ __launch_bounds__(512) void qkv_gemm_kernel(
    const u16* __restrict__ hb,
    const u16* __restrict__ qwb, const u16* __restrict__ kwb, const u16* __restrict__ vwb,
    u16* __restrict__ part)
{
  __shared__ u16 lds[3 * 24576];
  const int lin = blockIdx.y * 16 + blockIdx.x;   // 0..287, dispatch-linear
  const int swz = (lin & 7) * 36 + (lin >> 3);    // bijective XCD chunking
  const int m0  = (swz & 15) * 128;
  const int by  = swz >> 4;                       // 0..17
  const int k0  = blockIdx.z * KSPLIT_LEN;
  u16* Cz = part + (size_t)blockIdx.z * S_LEN * NQKV;
  const u16* Wp; size_t coff; int n0;
  if (by < 14)      { Wp = qwb; n0 = by * 256;        coff = n0; }
  else if (by < 16) { Wp = kwb; n0 = (by - 14) * 256; coff = HID + n0; }
  else              { Wp = vwb; n0 = (by - 16) * 256; coff = HID + KVD + n0; }
  gemm_core_128x256(lds, hb + (size_t)m0 * HID + k0,
                    Wp + (size_t)n0 * HID + k0,
                    Cz + (size_t)m0 * NQKV + coff, NQKV, HID, KSPLIT_LEN / 64);
}

// O-proj: partials [2][S][HID]; grid (16, 14, 2); XCD swizzle (224=8*28)
__global__ __launch_bounds__(512) void oproj_gemm_kernel(
    const u16* __restrict__ ao, const u16* __restrict__ owb, u16* __restrict__ part)
{
  __shared__ u16 lds[3 * 24576];
  const int lin = blockIdx.y * 16 + blockIdx.x;   // 0..223
  const int swz = (lin & 7) * 28 + (lin >> 3);
  const int m0  = (swz & 15) * 128;
  const int n0  = (swz >> 4) * 256;
  const int k0  = blockIdx.z * KSPLIT_LEN;
  u16* Cz = part + (size_t)blockIdx.z * S_LEN * HID;
  gemm_core_128x256(lds, ao + (size_t)m0 * HID + k0,
                    owb + (size_t)n0 * HID + k0,
                    Cz + (size_t)m0 * HID + n0, HID, HID, KSPLIT_LEN / 64);
}

// ------- QKV reduce: partial sum + bias + RoPE(+scale) + V-transpose -------
__global__ __launch_bounds__(256) void qkv_reduce_kernel(
    const u16* __restrict__ part,
    const float* __restrict__ q_b, const float* __restrict__ k_b,
    const float* __restrict__ v_b,
    const float* __restrict__ cosb, const float* __restrict__ sinb,
    u16* __restrict__ qbuf, u16* __restrict__ kbuf, u16* __restrict__ vtb)
{
  const int s   = blockIdx.y;
  const int c   = blockIdx.x * 256 + threadIdx.x;   // 0..2303
  const int seg = c >> 6;
  const int d   = c & 63;
  const u16* p0 = part + (size_t)s * NQKV;
  const u16* p1 = p0 + (size_t)S_LEN * NQKV;

  if (seg < 28) {
    const int base = seg * 128;
    const float lo = bf2f(p0[base + d])      + bf2f(p1[base + d])      + q_b[base + d];
    const float hi = bf2f(p0[base + d + 64]) + bf2f(p1[base + d + 64]) + q_b[base + d + 64];
    const float cc = cosb[s * HD + d];
    const float ss = sinb[s * HD + d];
    qbuf[(size_t)s * HID + base + d]      = f2bf((lo * cc - hi * ss) * QK_SCALE_L2E);
    qbuf[(size_t)s * HID + base + d + 64] = f2bf((lo * ss + hi * cc) * QK_SCALE_L2E);
  } else if (seg < 32) {
    const int hh = seg - 28;
    const int base = HID + hh * 128;
    const int bb = hh * 128;
    const float lo = bf2f(p0[base + d])      + bf2f(p1[base + d])      + k_b[bb + d];
    const float hi = bf2f(p0[base + d + 64]) + bf2f(p1[base + d + 64]) + k_b[bb + d + 64];
    const float cc = cosb[s * HD + d];
    const float ss = sinb[s * HD + d];
    kbuf[(size_t)s * KVD + bb + d]      = f2bf(lo * cc - hi * ss);
    kbuf[(size_t)s * KVD + bb + d + 64] = f2bf(lo * ss + hi * cc);
  } else {
    const int hh = seg - 32;
    const int base = HID + KVD + hh * 128;
    const int bb = hh * 128;
    const float lo = bf2f(p0[base + d])      + bf2f(p1[base + d])      + v_b[bb + d];
    const float hi = bf2f(p0[base + d + 64]) + bf2f(p1[base + d + 64]) + v_b[bb + d + 64];
    vtb[(size_t)(bb + d) * S_LEN + s]      = f2bf(lo);
    vtb[(size_t)(bb + d + 64) * S_LEN + s] = f2bf(hi);
  }
}

// ------- O-proj reduce: f32 out = p0 + p1 -------
__global__ __launch_bounds__(256) void o_reduce_kernel(
    const u16* __restrict__ part, float* __restrict__ out)
{
  const int i = blockIdx.x * 256 + threadIdx.x;   // 4 elems each
  const uint2 a = ((const uint2*)part)[i];
  const uint2 b = ((const uint2*)(part + (size_t)S_LEN * HID))[i];
  float4 o;
  o.x = bf2f((u16)(a.x & 0xffff)) + bf2f((u16)(b.x & 0xffff));
  o.y = bf2f((u16)(a.x >> 16))    + bf2f((u16)(b.x >> 16));
  o.z = bf2f((u16)(a.y & 0xffff)) + bf2f((u16)(b.y & 0xffff));
  o.w = bf2f((u16)(a.y >> 16))    + bf2f((u16)(b.y >> 16));
  ((float4*)out)[i] = o;
}

// ---------------- Flash attention (causal, GQA) ----------------
// 4 waves x 32 q-rows = 128-row tile; causal-paired tiles (lo, 15-lo) ->
// 34 uniform KV iters. K/V dbuf prefetch-before-compute (proven R4 sync).
// K/V fragments reused across 2 q-subtiles: LDS reads per MFMA halved.
// T13 defer-max, ones-MFMA row-sum, native cvt. LDS 80KB -> 2 blocks/CU.
__global__ __launch_bounds__(256) void attn_kernel(
    const u16* __restrict__ qb, const u16* __restrict__ kb,
    const u16* __restrict__ vtb, u16* __restrict__ ao)
{
  __shared__ u16 Ks[2][64 * 128];   // [kv][d], swizzled   (32KB)
  __shared__ u16 Vts[2][128 * 64];  // [d][kv], swizzled   (32KB)
  __shared__ u16 Ps[4][32 * 64];    // per-wave P, swizzled (16KB)

  const int h   = blockIdx.y;
  const int kvh = h / REP;
  const int lo  = blockIdx.x;       // 0..7 (128-row tiles 0..15)
  const int hi  = 15 - lo;
  const int J1  = 2 * lo + 2;       // first-half KV-iter count
  const int t   = threadIdx.x;
  const int w   = t >> 6;
  const int l   = t & 63;
  const int lr  = l & 15;
  const int lg  = l >> 4;
  const int sw  = (lr & 7) << 3;
  const f32x4 fz = {0.f, 0.f, 0.f, 0.f};
  short8 onesv;
#pragma unroll
  for (int i = 0; i < 8; ++i) onesv[i] = (short)0x3F80;  // bf16 1.0

  const u16* kbh  = kb + kvh * HD;
  const u16* vtbh = vtb + (size_t)kvh * HD * S_LEN;

  int tile = lo;
  int qrow0 = tile * 128 + w * 32;  // wave's first q row
  short8 qf[2][4];
#pragma unroll
  for (int mi = 0; mi < 2; ++mi) {
    const u16* qrow = qb + (size_t)(qrow0 + mi * 16 + lr) * HID + h * HD;
#pragma unroll
    for (int dk = 0; dk < 4; ++dk)
      qf[mi][dk] = *(const short8*)(qrow + dk * 32 + lg * 8);
  }

  float m_r[2][4];
  f32x4 lacc[2];
  f32x4 o_acc[2][8];
#pragma unroll
  for (int mi = 0; mi < 2; ++mi) {
#pragma unroll
    for (int r = 0; r < 4; ++r) m_r[mi][r] = -1e30f;
    lacc[mi] = fz;
#pragma unroll
    for (int db = 0; db < 8; ++db) o_acc[mi][db] = fz;
  }

  // ---- prologue: stage kv tile 0 into buf 0 ----
#pragma unroll
  for (int i = 0; i < 4; ++i) {
    const int e  = (i * 256 + t) * 8;
    const int rk = e >> 7;
    const int ck = (e & 127) ^ ((rk & 7) << 3);
    GLL16(kbh + (size_t)rk * KVD + ck, &Ks[0][0] + e);
    const int rv = e >> 6;
    const int cv = (e & 63) ^ ((rv & 7) << 3);
    GLL16(vtbh + (size_t)rv * S_LEN + cv, &Vts[0][0] + e);
  }
  __syncthreads();

#pragma unroll 1
  for (int j = 0; j < 34; ++j) {
    const int buf = j & 1;
    // ---- issue prefetch of next kv tile into buf^1 ----
    if (j + 1 < 34) {
      const int jn  = j + 1;
      const int kvn = ((jn < J1) ? jn : (jn - J1)) * 64;
#pragma unroll
      for (int i = 0; i < 4; ++i) {
        const int e  = (i * 256 + t) * 8;
        const int rk = e >> 7;
        const int ck = (e & 127) ^ ((rk & 7) << 3);
        GLL16(kbh + (size_t)(kvn + rk) * KVD + ck, &Ks[buf ^ 1][0] + e);
        const int rv = e >> 6;
        const int cv = (e & 63) ^ ((rv & 7) << 3);
        GLL16(vtbh + (size_t)rv * S_LEN + kvn + cv, &Vts[buf ^ 1][0] + e);
      }
    }

    const int kv0 = ((j < J1) ? j : (j - J1)) * 64;
    const u16* ks = &Ks[buf][0];
    const u16* vs = &Vts[buf][0];

    // ---- QK^T : S[2x16 q x 64 kv] per wave; kf reused across q-subtiles ----
    f32x4 sacc[2][4];
#pragma unroll
    for (int mi = 0; mi < 2; ++mi)
#pragma unroll
      for (int kvt = 0; kvt < 4; ++kvt) sacc[mi][kvt] = fz;
    __builtin_amdgcn_s_setprio(1);
#pragma unroll
    for (int kvt = 0; kvt < 4; ++kvt) {
#pragma unroll
      for (int dk = 0; dk < 4; ++dk) {
        const short8 kf = *(const short8*)(ks + (kvt * 16 + lr) * 128 + ((dk * 32 + lg * 8) ^ sw));
        sacc[0][kvt] = __builtin_amdgcn_mfma_f32_16x16x32_bf16(qf[0][dk], kf, sacc[0][kvt], 0, 0, 0);
        sacc[1][kvt] = __builtin_amdgcn_mfma_f32_16x16x32_bf16(qf[1][dk], kf, sacc[1][kvt], 0, 0, 0);
      }
    }
    __builtin_amdgcn_s_setprio(0);

    const bool maskit = (j >= J1 - 2 && j < J1) || (j >= 32);
    if (maskit) {  // tiles intersecting the diagonal: causal mask
#pragma unroll
      for (int mi = 0; mi < 2; ++mi) {
#pragma unroll
        for (int kvt = 0; kvt < 4; ++kvt) {
          const int col = kv0 + kvt * 16 + lr;
#pragma unroll
          for (int r = 0; r < 4; ++r) {
            if (col > qrow0 + mi * 16 + lg * 4 + r) sacc[mi][kvt][r] = -1e30f;
          }
        }
      }
    }

    // ---- online softmax: max-reduce + defer-max (THR=8) ----
    float tmr[2][4];
    bool ok = true;
#pragma unroll
    for (int mi = 0; mi < 2; ++mi) {
#pragma unroll
      for (int r = 0; r < 4; ++r) {
        float tm = fmaxf(fmaxf(sacc[mi][0][r], sacc[mi][1][r]),
                         fmaxf(sacc[mi][2][r], sacc[mi][3][r]));
        tm = fmaxf(tm, __shfl_xor(tm, 1));
        tm = fmaxf(tm, __shfl_xor(tm, 2));
        tm = fmaxf(tm, __shfl_xor(tm, 4));
        tm = fmaxf(tm, __shfl_xor(tm, 8));
        tmr[mi][r] = tm;
        ok = ok && (tm <= m_r[mi][r] + 8.f);
      }
    }
    if (!__all(ok)) {
#pragma unroll
      for (int mi = 0; mi < 2; ++mi) {
#pragma unroll
        for (int r = 0; r < 4; ++r) {
          const float mn = fmaxf(m_r[mi][r], tmr[mi][r]);
          const float alpha = exp2f(m_r[mi][r] - mn);
          m_r[mi][r] = mn;
          lacc[mi][r] *= alpha;
#pragma unroll
          for (int db = 0; db < 8; ++db) o_acc[mi][db][r] *= alpha;
        }
      }
    }

    // ---- P = exp2(S - m) -> per-wave LDS (bf16, swizzled) ----
#pragma unroll
    for (int mi = 0; mi < 2; ++mi) {
#pragma unroll
      for (int kvt = 0; kvt < 4; ++kvt) {
#pragma unroll
        for (int r = 0; r < 4; ++r) {
          const int prow = mi * 16 + lg * 4 + r;
          Ps[w][prow * 64 + ((kvt * 16 + lr) ^ ((prow & 7) << 3))] =
              nbf(exp2f(sacc[mi][kvt][r] - m_r[mi][r]));
        }
      }
    }

    short8 pf[2][2];
#pragma unroll
    for (int mi = 0; mi < 2; ++mi)
#pragma unroll
      for (int ks2 = 0; ks2 < 2; ++ks2)
        pf[mi][ks2] = *(const short8*)(&Ps[w][0] + (mi * 16 + lr) * 64 + ((ks2 * 32 + lg * 8) ^ sw));

    // ---- PV (+ ones-MFMA row-sum); vf reused across q-subtiles ----
    __builtin_amdgcn_s_setprio(1);
#pragma unroll
    for (int mi = 0; mi < 2; ++mi) {
      lacc[mi] = __builtin_amdgcn_mfma_f32_16x16x32_bf16(pf[mi][0], onesv, lacc[mi], 0, 0, 0);
      lacc[mi] = __builtin_amdgcn_mfma_f32_16x16x32_bf16(pf[mi][1], onesv, lacc[mi], 0, 0, 0);
    }
#pragma unroll
    for (int db = 0; db < 8; ++db) {
#pragma unroll
      for (int ks2 = 0; ks2 < 2; ++ks2) {
        const short8 vf = *(const short8*)(vs + (db * 16 + lr) * 64 + ((ks2 * 32 + lg * 8) ^ sw));
        o_acc[0][db] = __builtin_amdgcn_mfma_f32_16x16x32_bf16(pf[0][ks2], vf, o_acc[0][db], 0, 0, 0);
        o_acc[1][db] = __builtin_amdgcn_mfma_f32_16x16x32_bf16(pf[1][ks2], vf, o_acc[1][db], 0, 0, 0);
      }
    }
    __builtin_amdgcn_s_setprio(0);

    // ---- end-of-half: epilogue + switch to hi tile ----
    const bool last_of_half = (j == J1 - 1) || (j == 33);
    if (last_of_half) {
#pragma unroll
      for (int mi = 0; mi < 2; ++mi) {
#pragma unroll
        for (int r = 0; r < 4; ++r) {
          const float inv = 1.0f / lacc[mi][r];
          u16* orow = ao + (size_t)(qrow0 + mi * 16 + lg * 4 + r) * HID + h * HD;
#pragma unroll
          for (int db = 0; db < 8; ++db)
            orow[db * 16 + lr] = nbf(o_acc[mi][db][r] * inv);
        }
      }
      if (j != 33) {
        tile = hi;
        qrow0 = tile * 128 + w * 32;
#pragma unroll
        for (int mi = 0; mi < 2; ++mi) {
          const u16* qrow = qb + (size_t)(qrow0 + mi * 16 + lr) * HID + h * HD;
#pragma unroll
          for (int dk = 0; dk < 4; ++dk)
            qf[mi][dk] = *(const short8*)(qrow + dk * 32 + lg * 8);
#pragma unroll
          for (int r = 0; r < 4; ++r) m_r[mi][r] = -1e30f;
          lacc[mi] = fz;
#pragma unroll
          for (int db = 0; db < 8; ++db) o_acc[mi][db] = fz;
        }
      }
    }
    __syncthreads();  // drains prefetch + guards buf reuse
  }
}

// ---------------- launch ----------------
extern "C" void kernel_launch(void* const* d_in, const int* in_sizes, int n_in,
                              void* d_out, int out_size, void* d_ws, size_t ws_size,
                              hipStream_t stream) {
  const float* hidden = (const float*)d_in[0];
  const float* cosb = (const float*)d_in[2];
  const float* sinb = (const float*)d_in[3];
  const float* q_w  = (const float*)d_in[4];
  const float* q_b  = (const float*)d_in[5];
  const float* k_w  = (const float*)d_in[6];
  const float* k_b  = (const float*)d_in[7];
  const float* v_w  = (const float*)d_in[8];
  const float* v_b  = (const float*)d_in[9];
  const float* o_w  = (const float*)d_in[10];
  float* out = (float*)d_out;

  char* p = (char*)d_ws;
  u16* hb   = (u16*)p; p += (size_t)S_LEN * HID * 2;
  u16* qwb  = (u16*)p; p += (size_t)HID * HID * 2;
  u16* kwb  = (u16*)p; p += (size_t)KVD * HID * 2;
  u16* vwb  = (u16*)p; p += (size_t)KVD * HID * 2;
  u16* owb  = (u16*)p; p += (size_t)HID * HID * 2;
  u16* qbuf = (u16*)p; p += (size_t)S_LEN * HID * 2;
  u16* kbuf = (u16*)p; p += (size_t)S_LEN * KVD * 2;
  u16* vtb  = (u16*)p; p += (size_t)KVD * S_LEN * 2;
  u16* ao   = (u16*)p; p += (size_t)S_LEN * HID * 2;
  u16* part = (u16*)p; p += (size_t)2 * S_LEN * NQKV * 2;  // shared qkv/oproj partials
  if ((size_t)(p - (char*)d_ws) > ws_size) return;

  cvt_all_kernel<<<dim3(1024, 5), 256, 0, stream>>>(
      hidden, q_w, k_w, v_w, o_w, hb, qwb, kwb, vwb, owb);

  qkv_gemm_kernel<<<dim3(16, 18, 2), 512, 0, stream>>>(hb, qwb, kwb, vwb, part);
  qkv_reduce_kernel<<<dim3(9, S_LEN), 256, 0, stream>>>(
      part, q_b, k_b, v_b, cosb, sinb, qbuf, kbuf, vtb);

  attn_kernel<<<dim3(8, 28), 256, 0, stream>>>(qbuf, kbuf, vtb, ao);

  oproj_gemm_kernel<<<dim3(16, 14, 2), 512, 0, stream>>>(ao, owb, part);
  o_reduce_kernel<<<(S_LEN * HID / 4) / 256, 256, 0, stream>>>(part, out);
}

// Round 10
// 329.131 us; speedup vs baseline: 1.0065x; 1.0065x over previous
//
#include <hip/hip_runtime.h>
#include <hip/hip_bf16.h>
#include <stdint.h>
#include <stddef.h>

#define S_LEN 2048
#define HID   3584
#define NH    28
#define NKV   4
#define HD    128
#define REP   7
#define KVD   512
#define NQKV  4608          // 3584 + 512 + 512
#define KSPLIT_LEN 1792     // 3584 / 2
// QK scale with log2(e) folded in: softmax uses exp2
#define QK_SCALE_L2E 0.12752462155f   // (1/sqrt(128)) * log2(e)

typedef unsigned short u16;
typedef short short8 __attribute__((ext_vector_type(8)));
typedef float f32x4 __attribute__((ext_vector_type(4)));

__device__ __forceinline__ u16 f2bf(float f) {
  union { float f; uint32_t u; } v; v.f = f;
  uint32_t r = v.u + 0x7fffu + ((v.u >> 16) & 1u);
  return (u16)(r >> 16);
}
__device__ __forceinline__ float bf2f(u16 u) {
  union { uint32_t u; float f; } v; v.u = ((uint32_t)u) << 16;
  return v.f;
}
__device__ __forceinline__ u16 nbf(float f) {  // native 1-op RNE cvt
  __hip_bfloat16 h = __float2bfloat16(f);
  return *reinterpret_cast<u16*>(&h);
}

#define GLL16(gp, lp) __builtin_amdgcn_global_load_lds( \
    (const __attribute__((address_space(1))) void*)(gp), \
    (__attribute__((address_space(3))) void*)(lp), 16, 0, 0)

// ---------------- f32 -> bf16 bulk convert (all 5 buffers, one launch) -------
__global__ __launch_bounds__(256) void cvt_all_kernel(
    const float* __restrict__ h, const float* __restrict__ qw,
    const float* __restrict__ kw, const float* __restrict__ vw,
    const float* __restrict__ ow,
    u16* __restrict__ hb, u16* __restrict__ qwb, u16* __restrict__ kwb,
    u16* __restrict__ vwb, u16* __restrict__ owb)
{
  const float* src; u16* dst; int n4;
  switch (blockIdx.y) {
    case 0: src = h;  dst = hb;  n4 = S_LEN * HID / 4; break;
    case 1: src = qw; dst = qwb; n4 = HID * HID / 4;   break;
    case 2: src = kw; dst = kwb; n4 = KVD * HID / 4;   break;
    case 3: src = vw; dst = vwb; n4 = KVD * HID / 4;   break;
    default: src = ow; dst = owb; n4 = HID * HID / 4;  break;
  }
  int i = blockIdx.x * blockDim.x + threadIdx.x;
  const int stride = gridDim.x * blockDim.x;
  for (; i < n4; i += stride) {
    float4 v = reinterpret_cast<const float4*>(src)[i];
    uint2 o;
    o.x = (uint32_t)f2bf(v.x) | ((uint32_t)f2bf(v.y) << 16);
    o.y = (uint32_t)f2bf(v.z) | ((uint32_t)f2bf(v.w) << 16);
    reinterpret_cast<uint2*>(dst)[i] = o;
  }
}

// ---- GEMM core: 128x256 tile, 8 waves (2Mx4N, wave=64x64), BK=64,
// triple-buffered LDS, counted vmcnt (vmcnt(6) steady, 0 only at tail),
// 2-phase-per-K-tile barrier rhythm (benched-best 298us config).
__device__ __forceinline__ void gemm_core_128x256(
    u16* lds, const u16* __restrict__ A, const u16* __restrict__ W,
    u16* __restrict__ C, int ldC, int lda, int T)
{
  const int t  = threadIdx.x;       // 0..511
  const int l  = t & 63;
  const int w  = t >> 6;            // 0..7
  const int lr = l & 15;
  const int lg = l >> 4;
  const int wm = (w >> 2) << 6;     // 0 or 64
  const int wn = (w & 3) << 6;      // 0,64,128,192
  const int sw = (lr & 7) << 3;

  const f32x4 fz = {0.f, 0.f, 0.f, 0.f};
  f32x4 acc[4][4];
#pragma unroll
  for (int i = 0; i < 4; ++i)
#pragma unroll
    for (int j = 0; j < 4; ++j) acc[i][j] = fz;

#define LD_A(kt, buf, i_) do {                                        \
    const int e_ = ((i_) * 512 + t) * 8;                              \
    const int r_ = e_ >> 6;                                           \
    const int c_ = (e_ & 63) ^ ((r_ & 7) << 3);                       \
    GLL16(A + (size_t)(kt) * 64 + (size_t)r_ * lda + c_, (buf) + e_); \
  } while (0)
#define LD_B(kt, buf, i_) do {                                        \
    const int e_ = ((i_) * 512 + t) * 8;                              \
    const int r_ = e_ >> 6;                                           \
    const int c_ = (e_ & 63) ^ ((r_ & 7) << 3);                       \
    GLL16(W + (size_t)(kt) * 64 + (size_t)r_ * lda + c_, (buf) + 8192 + e_); \
  } while (0)
#define STAGE_FULL(kt, buf) do {                                      \
    LD_A(kt, buf, 0); LD_A(kt, buf, 1);                               \
    LD_B(kt, buf, 0); LD_B(kt, buf, 1); LD_B(kt, buf, 2); LD_B(kt, buf, 3); \
  } while (0)

  STAGE_FULL(0, lds);
  STAGE_FULL(1, lds + 24576);

#pragma unroll 1
  for (int tk = 0; tk < T; ++tk) {
    if (tk + 1 < T) { asm volatile("s_waitcnt vmcnt(6)" ::: "memory"); }
    else            { asm volatile("s_waitcnt vmcnt(0)" ::: "memory"); }
    __builtin_amdgcn_sched_barrier(0);
    __builtin_amdgcn_s_barrier();
    __builtin_amdgcn_sched_barrier(0);

    const u16* As_ = lds + (tk % 3) * 24576;
    const u16* Bs_ = As_ + 8192;
    u16* nb = lds + ((tk + 2) % 3) * 24576;
    const bool pre = (tk + 2 < T);
    short8 af[4], bfr[4];

    // ================= phase 0 (kk = 0) =================
#pragma unroll
    for (int mi = 0; mi < 4; ++mi)
      af[mi] = *(const short8*)(As_ + (wm + mi * 16 + lr) * 64 + ((lg * 8) ^ sw));
#pragma unroll
    for (int ni = 0; ni < 4; ++ni)
      bfr[ni] = *(const short8*)(Bs_ + (wn + ni * 16 + lr) * 64 + ((lg * 8) ^ sw));
    if (pre) { LD_A(tk + 2, nb, 0); LD_A(tk + 2, nb, 1); LD_B(tk + 2, nb, 0); }
    __builtin_amdgcn_sched_barrier(0);
    __builtin_amdgcn_s_barrier();
    __builtin_amdgcn_sched_barrier(0);
    __builtin_amdgcn_s_setprio(1);
#pragma unroll
    for (int mi = 0; mi < 4; ++mi)
#pragma unroll
      for (int ni = 0; ni < 4; ++ni)
        acc[mi][ni] = __builtin_amdgcn_mfma_f32_16x16x32_bf16(af[mi], bfr[ni], acc[mi][ni], 0, 0, 0);
    __builtin_amdgcn_s_setprio(0);
    __builtin_amdgcn_sched_barrier(0);
    __builtin_amdgcn_s_barrier();
    __builtin_amdgcn_sched_barrier(0);

    // ================= phase 1 (kk = 1) =================
#pragma unroll
    for (int mi = 0; mi < 4; ++mi)
      af[mi] = *(const short8*)(As_ + (wm + mi * 16 + lr) * 64 + ((32 + lg * 8) ^ sw));
#pragma unroll
    for (int ni = 0; ni < 4; ++ni)
      bfr[ni] = *(const short8*)(Bs_ + (wn + ni * 16 + lr) * 64 + ((32 + lg * 8) ^ sw));
    if (pre) { LD_B(tk + 2, nb, 1); LD_B(tk + 2, nb, 2); LD_B(tk + 2, nb, 3); }
    __builtin_amdgcn_sched_barrier(0);
    __builtin_amdgcn_s_barrier();
    __builtin_amdgcn_sched_barrier(0);
    __builtin_amdgcn_s_setprio(1);
#pragma unroll
    for (int mi = 0; mi < 4; ++mi)
#pragma unroll
      for (int ni = 0; ni < 4; ++ni)
        acc[mi][ni] = __builtin_amdgcn_mfma_f32_16x16x32_bf16(af[mi], bfr[ni], acc[mi][ni], 0, 0, 0);
    __builtin_amdgcn_s_setprio(0);
  }
#undef STAGE_FULL
#undef LD_A
#undef LD_B

#pragma unroll
  for (int ni = 0; ni < 4; ++ni) {
    const int n = wn + ni * 16 + lr;
#pragma unroll
    for (int mi = 0; mi < 4; ++mi) {
#pragma unroll
      for (int r = 0; r < 4; ++r) {
        const int m = wm + mi * 16 + lg * 4 + r;
        C[(size_t)m * ldC + n] = f2bf(acc[mi][ni][r]);
      }
    }
  }
}

// QKV: partials [2][S][NQKV]; grid (16, 18, 2); XCD-chunk swizzle (288=8*36)
__global__ __launch_bounds__(512) void qkv_gemm_kernel(
    const u16* __restrict__ hb,
    const u16* __restrict__ qwb, const u16* __restrict__ kwb, const u16* __restrict__ vwb,
    u16* __restrict__ part)
{
  __shared__ u16 lds[3 * 24576];
  const int lin = blockIdx.y * 16 + blockIdx.x;   // 0..287, dispatch-linear
  const int swz = (lin & 7) * 36 + (lin >> 3);    // bijective XCD chunking
  const int m0  = (swz & 15) * 128;
  const int by  = swz >> 4;                       // 0..17
  const int k0  = blockIdx.z * KSPLIT_LEN;
  u16* Cz = part + (size_t)blockIdx.z * S_LEN * NQKV;
  const u16* Wp; size_t coff; int n0;
  if (by < 14)      { Wp = qwb; n0 = by * 256;        coff = n0; }
  else if (by < 16) { Wp = kwb; n0 = (by - 14) * 256; coff = HID + n0; }
  else              { Wp = vwb; n0 = (by - 16) * 256; coff = HID + KVD + n0; }
  gemm_core_128x256(lds, hb + (size_t)m0 * HID + k0,
                    Wp + (size_t)n0 * HID + k0,
                    Cz + (size_t)m0 * NQKV + coff, NQKV, HID, KSPLIT_LEN / 64);
}

// O-proj: partials [2][S][HID]; grid (16, 14, 2); XCD swizzle (224=8*28)
__global__ __launch_bounds__(512) void oproj_gemm_kernel(
    const u16* __restrict__ ao, const u16* __restrict__ owb, u16* __restrict__ part)
{
  __shared__ u16 lds[3 * 24576];
  const int lin = blockIdx.y * 16 + blockIdx.x;   // 0..223
  const int swz = (lin & 7) * 28 + (lin >> 3);
  const int m0  = (swz & 15) * 128;
  const int n0  = (swz >> 4) * 256;
  const int k0  = blockIdx.z * KSPLIT_LEN;
  u16* Cz = part + (size_t)blockIdx.z * S_LEN * HID;
  gemm_core_128x256(lds, ao + (size_t)m0 * HID + k0,
                    owb + (size_t)n0 * HID + k0,
                    Cz + (size_t)m0 * HID + n0, HID, HID, KSPLIT_LEN / 64);
}

// ------- QKV reduce: partial sum + bias + RoPE(+scale) + V-transpose -------
__global__ __launch_bounds__(256) void qkv_reduce_kernel(
    const u16* __restrict__ part,
    const float* __restrict__ q_b, const float* __restrict__ k_b,
    const float* __restrict__ v_b,
    const float* __restrict__ cosb, const float* __restrict__ sinb,
    u16* __restrict__ qbuf, u16* __restrict__ kbuf, u16* __restrict__ vtb)
{
  const int s   = blockIdx.y;
  const int c   = blockIdx.x * 256 + threadIdx.x;   // 0..2303
  const int seg = c >> 6;
  const int d   = c & 63;
  const u16* p0 = part + (size_t)s * NQKV;
  const u16* p1 = p0 + (size_t)S_LEN * NQKV;

  if (seg < 28) {
    const int base = seg * 128;
    const float lo = bf2f(p0[base + d])      + bf2f(p1[base + d])      + q_b[base + d];
    const float hi = bf2f(p0[base + d + 64]) + bf2f(p1[base + d + 64]) + q_b[base + d + 64];
    const float cc = cosb[s * HD + d];
    const float ss = sinb[s * HD + d];
    qbuf[(size_t)s * HID + base + d]      = f2bf((lo * cc - hi * ss) * QK_SCALE_L2E);
    qbuf[(size_t)s * HID + base + d + 64] = f2bf((lo * ss + hi * cc) * QK_SCALE_L2E);
  } else if (seg < 32) {
    const int hh = seg - 28;
    const int base = HID + hh * 128;
    const int bb = hh * 128;
    const float lo = bf2f(p0[base + d])      + bf2f(p1[base + d])      + k_b[bb + d];
    const float hi = bf2f(p0[base + d + 64]) + bf2f(p1[base + d + 64]) + k_b[bb + d + 64];
    const float cc = cosb[s * HD + d];
    const float ss = sinb[s * HD + d];
    kbuf[(size_t)s * KVD + bb + d]      = f2bf(lo * cc - hi * ss);
    kbuf[(size_t)s * KVD + bb + d + 64] = f2bf(lo * ss + hi * cc);
  } else {
    const int hh = seg - 32;
    const int base = HID + KVD + hh * 128;
    const int bb = hh * 128;
    const float lo = bf2f(p0[base + d])      + bf2f(p1[base + d])      + v_b[bb + d];
    const float hi = bf2f(p0[base + d + 64]) + bf2f(p1[base + d + 64]) + v_b[bb + d + 64];
    vtb[(size_t)(bb + d) * S_LEN + s]      = f2bf(lo);
    vtb[(size_t)(bb + d + 64) * S_LEN + s] = f2bf(hi);
  }
}

// ------- O-proj reduce: f32 out = p0 + p1 -------
__global__ __launch_bounds__(256) void o_reduce_kernel(
    const u16* __restrict__ part, float* __restrict__ out)
{
  const int i = blockIdx.x * 256 + threadIdx.x;   // 4 elems each
  const uint2 a = ((const uint2*)part)[i];
  const uint2 b = ((const uint2*)(part + (size_t)S_LEN * HID))[i];
  float4 o;
  o.x = bf2f((u16)(a.x & 0xffff)) + bf2f((u16)(b.x & 0xffff));
  o.y = bf2f((u16)(a.x >> 16))    + bf2f((u16)(b.x >> 16));
  o.z = bf2f((u16)(a.y & 0xffff)) + bf2f((u16)(b.y & 0xffff));
  o.w = bf2f((u16)(a.y >> 16))    + bf2f((u16)(b.y >> 16));
  ((float4*)out)[i] = o;
}

// ---------------- Flash attention (causal, GQA) ----------------
// 2 waves x 32 q-rows = 64-row tile; causal pairing (lo, 31-lo) -> 33
// uniform KV iters; grid 16x28 = 448 blocks, LDS 72KB -> 2 blocks/CU.
// K/V fragments reused across 2 q-subtiles per wave: LDS reads per MFMA
// halved (68 MFMA / 36 b128-reads vs 34/34). Proven R7 sync: dbuf
// prefetch-before-compute, one barrier/iter. T13 defer-max, ones-MFMA
// row-sum, native cvt.
__global__ __launch_bounds__(128) void attn_kernel(
    const u16* __restrict__ qb, const u16* __restrict__ kb,
    const u16* __restrict__ vtb, u16* __restrict__ ao)
{
  __shared__ u16 Ks[2][64 * 128];   // [kv][d], swizzled   (32KB)
  __shared__ u16 Vts[2][128 * 64];  // [d][kv], swizzled   (32KB)
  __shared__ u16 Ps[2][32 * 64];    // per-wave P, swizzled (8KB)

  const int h   = blockIdx.y;
  const int kvh = h / REP;
  const int lo  = blockIdx.x;       // 0..15
  const int hi  = 31 - lo;
  const int t   = threadIdx.x;      // 0..127
  const int w   = t >> 6;           // 0..1
  const int l   = t & 63;
  const int lr  = l & 15;
  const int lg  = l >> 4;
  const int sw  = (lr & 7) << 3;
  const f32x4 fz = {0.f, 0.f, 0.f, 0.f};
  short8 onesv;
#pragma unroll
  for (int i = 0; i < 8; ++i) onesv[i] = (short)0x3F80;  // bf16 1.0

  const u16* kbh  = kb + kvh * HD;
  const u16* vtbh = vtb + (size_t)kvh * HD * S_LEN;

  int tile = lo;
  int qrow0 = tile * 64 + w * 32;   // wave's first q row
  short8 qf[2][4];
#pragma unroll
  for (int mi = 0; mi < 2; ++mi) {
    const u16* qrow = qb + (size_t)(qrow0 + mi * 16 + lr) * HID + h * HD;
#pragma unroll
    for (int dk = 0; dk < 4; ++dk)
      qf[mi][dk] = *(const short8*)(qrow + dk * 32 + lg * 8);
  }

  float m_r[2][4];
  f32x4 lacc[2];
  f32x4 o_acc[2][8];
#pragma unroll
  for (int mi = 0; mi < 2; ++mi) {
#pragma unroll
    for (int r = 0; r < 4; ++r) m_r[mi][r] = -1e30f;
    lacc[mi] = fz;
#pragma unroll
    for (int db = 0; db < 8; ++db) o_acc[mi][db] = fz;
  }

  // ---- prologue: stage kv tile 0 into buf 0 (128 thr: 8+8 loads each) ----
#pragma unroll
  for (int i = 0; i < 8; ++i) {
    const int e  = (i * 128 + t) * 8;
    const int rk = e >> 7;
    const int ck = (e & 127) ^ ((rk & 7) << 3);
    GLL16(kbh + (size_t)rk * KVD + ck, &Ks[0][0] + e);
    const int rv = e >> 6;
    const int cv = (e & 63) ^ ((rv & 7) << 3);
    GLL16(vtbh + (size_t)rv * S_LEN + cv, &Vts[0][0] + e);
  }
  __syncthreads();

#pragma unroll 1
  for (int j = 0; j < 33; ++j) {
    const int buf = j & 1;
    // ---- issue prefetch of next kv tile into buf^1 ----
    if (j + 1 < 33) {
      const int jn  = j + 1;
      const int kvn = ((jn <= lo) ? jn : (jn - lo - 1)) * 64;
#pragma unroll
      for (int i = 0; i < 8; ++i) {
        const int e  = (i * 128 + t) * 8;
        const int rk = e >> 7;
        const int ck = (e & 127) ^ ((rk & 7) << 3);
        GLL16(kbh + (size_t)(kvn + rk) * KVD + ck, &Ks[buf ^ 1][0] + e);
        const int rv = e >> 6;
        const int cv = (e & 63) ^ ((rv & 7) << 3);
        GLL16(vtbh + (size_t)rv * S_LEN + kvn + cv, &Vts[buf ^ 1][0] + e);
      }
    }

    const int kv0 = ((j <= lo) ? j : (j - lo - 1)) * 64;
    const u16* ks = &Ks[buf][0];
    const u16* vs = &Vts[buf][0];

    // ---- QK^T : 2 subtiles share each K fragment ----
    f32x4 sacc[2][4];
#pragma unroll
    for (int mi = 0; mi < 2; ++mi)
#pragma unroll
      for (int kvt = 0; kvt < 4; ++kvt) sacc[mi][kvt] = fz;
    __builtin_amdgcn_s_setprio(1);
#pragma unroll
    for (int kvt = 0; kvt < 4; ++kvt) {
#pragma unroll
      for (int dk = 0; dk < 4; ++dk) {
        const short8 kf = *(const short8*)(ks + (kvt * 16 + lr) * 128 + ((dk * 32 + lg * 8) ^ sw));
        sacc[0][kvt] = __builtin_amdgcn_mfma_f32_16x16x32_bf16(qf[0][dk], kf, sacc[0][kvt], 0, 0, 0);
        sacc[1][kvt] = __builtin_amdgcn_mfma_f32_16x16x32_bf16(qf[1][dk], kf, sacc[1][kvt], 0, 0, 0);
      }
    }
    __builtin_amdgcn_s_setprio(0);

    const bool last_of_half = (j == lo) || (j == 32);
    if (last_of_half) {  // diagonal tile: causal mask
#pragma unroll
      for (int mi = 0; mi < 2; ++mi) {
#pragma unroll
        for (int kvt = 0; kvt < 4; ++kvt) {
          const int col = kv0 + kvt * 16 + lr;
#pragma unroll
          for (int r = 0; r < 4; ++r) {
            if (col > qrow0 + mi * 16 + lg * 4 + r) sacc[mi][kvt][r] = -1e30f;
          }
        }
      }
    }

    // ---- online softmax: max-reduce + defer-max (THR=8) ----
    float tmr[2][4];
    bool ok = true;
#pragma unroll
    for (int mi = 0; mi < 2; ++mi) {
#pragma unroll
      for (int r = 0; r < 4; ++r) {
        float tm = fmaxf(fmaxf(sacc[mi][0][r], sacc[mi][1][r]),
                         fmaxf(sacc[mi][2][r], sacc[mi][3][r]));
        tm = fmaxf(tm, __shfl_xor(tm, 1));
        tm = fmaxf(tm, __shfl_xor(tm, 2));
        tm = fmaxf(tm, __shfl_xor(tm, 4));
        tm = fmaxf(tm, __shfl_xor(tm, 8));
        tmr[mi][r] = tm;
        ok = ok && (tm <= m_r[mi][r] + 8.f);
      }
    }
    if (!__all(ok)) {
#pragma unroll
      for (int mi = 0; mi < 2; ++mi) {
#pragma unroll
        for (int r = 0; r < 4; ++r) {
          const float mn = fmaxf(m_r[mi][r], tmr[mi][r]);
          const float alpha = exp2f(m_r[mi][r] - mn);
          m_r[mi][r] = mn;
          lacc[mi][r] *= alpha;
#pragma unroll
          for (int db = 0; db < 8; ++db) o_acc[mi][db][r] *= alpha;
        }
      }
    }

    // ---- P = exp2(S - m) -> per-wave LDS (bf16, swizzled) ----
#pragma unroll
    for (int mi = 0; mi < 2; ++mi) {
#pragma unroll
      for (int kvt = 0; kvt < 4; ++kvt) {
#pragma unroll
        for (int r = 0; r < 4; ++r) {
          const int prow = mi * 16 + lg * 4 + r;
          Ps[w][prow * 64 + ((kvt * 16 + lr) ^ ((prow & 7) << 3))] =
              nbf(exp2f(sacc[mi][kvt][r] - m_r[mi][r]));
        }
      }
    }

    short8 pf[2][2];
#pragma unroll
    for (int mi = 0; mi < 2; ++mi)
#pragma unroll
      for (int ks2 = 0; ks2 < 2; ++ks2)
        pf[mi][ks2] = *(const short8*)(&Ps[w][0] + (mi * 16 + lr) * 64 + ((ks2 * 32 + lg * 8) ^ sw));

    // ---- PV (+ ones-MFMA row-sum); V fragments shared across subtiles ----
    __builtin_amdgcn_s_setprio(1);
#pragma unroll
    for (int mi = 0; mi < 2; ++mi) {
      lacc[mi] = __builtin_amdgcn_mfma_f32_16x16x32_bf16(pf[mi][0], onesv, lacc[mi], 0, 0, 0);
      lacc[mi] = __builtin_amdgcn_mfma_f32_16x16x32_bf16(pf[mi][1], onesv, lacc[mi], 0, 0, 0);
    }
#pragma unroll
    for (int db = 0; db < 8; ++db) {
#pragma unroll
      for (int ks2 = 0; ks2 < 2; ++ks2) {
        const short8 vf = *(const short8*)(vs + (db * 16 + lr) * 64 + ((ks2 * 32 + lg * 8) ^ sw));
        o_acc[0][db] = __builtin_amdgcn_mfma_f32_16x16x32_bf16(pf[0][ks2], vf, o_acc[0][db], 0, 0, 0);
        o_acc[1][db] = __builtin_amdgcn_mfma_f32_16x16x32_bf16(pf[1][ks2], vf, o_acc[1][db], 0, 0, 0);
      }
    }
    __builtin_amdgcn_s_setprio(0);

    // ---- end-of-half: epilogue + switch to hi tile ----
    if (last_of_half) {
#pragma unroll
      for (int mi = 0; mi < 2; ++mi) {
#pragma unroll
        for (int r = 0; r < 4; ++r) {
          const float inv = 1.0f / lacc[mi][r];
          u16* orow = ao + (size_t)(qrow0 + mi * 16 + lg * 4 + r) * HID + h * HD;
#pragma unroll
          for (int db = 0; db < 8; ++db)
            orow[db * 16 + lr] = nbf(o_acc[mi][db][r] * inv);
        }
      }
      if (j != 32) {
        tile = hi;
        qrow0 = tile * 64 + w * 32;
#pragma unroll
        for (int mi = 0; mi < 2; ++mi) {
          const u16* qrow = qb + (size_t)(qrow0 + mi * 16 + lr) * HID + h * HD;
#pragma unroll
          for (int dk = 0; dk < 4; ++dk)
            qf[mi][dk] = *(const short8*)(qrow + dk * 32 + lg * 8);
#pragma unroll
          for (int r = 0; r < 4; ++r) m_r[mi][r] = -1e30f;
          lacc[mi] = fz;
#pragma unroll
          for (int db = 0; db < 8; ++db) o_acc[mi][db] = fz;
        }
      }
    }
    __syncthreads();  // drains prefetch + guards buf reuse
  }
}

// ---------------- launch ----------------
extern "C" void kernel_launch(void* const* d_in, const int* in_sizes, int n_in,
                              void* d_out, int out_size, void* d_ws, size_t ws_size,
                              hipStream_t stream) {
  const float* hidden = (const float*)d_in[0];
  const float* cosb = (const float*)d_in[2];
  const float* sinb = (const float*)d_in[3];
  const float* q_w  = (const float*)d_in[4];
  const float* q_b  = (const float*)d_in[5];
  const float* k_w  = (const float*)d_in[6];
  const float* k_b  = (const float*)d_in[7];
  const float* v_w  = (const float*)d_in[8];
  const float* v_b  = (const float*)d_in[9];
  const float* o_w  = (const float*)d_in[10];
  float* out = (float*)d_out;

  char* p = (char*)d_ws;
  u16* hb   = (u16*)p; p += (size_t)S_LEN * HID * 2;
  u16* qwb  = (u16*)p; p += (size_t)HID * HID * 2;
  u16* kwb  = (u16*)p; p += (size_t)KVD * HID * 2;
  u16* vwb  = (u16*)p; p += (size_t)KVD * HID * 2;
  u16* owb  = (u16*)p; p += (size_t)HID * HID * 2;
  u16* qbuf = (u16*)p; p += (size_t)S_LEN * HID * 2;
  u16* kbuf = (u16*)p; p += (size_t)S_LEN * KVD * 2;
  u16* vtb  = (u16*)p; p += (size_t)KVD * S_LEN * 2;
  u16* ao   = (u16*)p; p += (size_t)S_LEN * HID * 2;
  u16* part = (u16*)p; p += (size_t)2 * S_LEN * NQKV * 2;  // shared qkv/oproj partials
  if ((size_t)(p - (char*)d_ws) > ws_size) return;

  cvt_all_kernel<<<dim3(1024, 5), 256, 0, stream>>>(
      hidden, q_w, k_w, v_w, o_w, hb, qwb, kwb, vwb, owb);

  qkv_gemm_kernel<<<dim3(16, 18, 2), 512, 0, stream>>>(hb, qwb, kwb, vwb, part);
  qkv_reduce_kernel<<<dim3(9, S_LEN), 256, 0, stream>>>(
      part, q_b, k_b, v_b, cosb, sinb, qbuf, kbuf, vtb);

  attn_kernel<<<dim3(16, 28), 128, 0, stream>>>(qbuf, kbuf, vtb, ao);

  oproj_gemm_kernel<<<dim3(16, 14, 2), 512, 0, stream>>>(ao, owb, part);
  o_reduce_kernel<<<(S_LEN * HID / 4) / 256, 256, 0, stream>>>(part, out);
}

// Round 11
// 296.291 us; speedup vs baseline: 1.1181x; 1.1108x over previous
//
#include <hip/hip_runtime.h>
#include <hip/hip_bf16.h>
#include <stdint.h>
#include <stddef.h>

#define S_LEN 2048
#define HID   3584
#define NH    28
#define NKV   4
#define HD    128
#define REP   7
#define KVD   512
#define NQKV  4608          // 3584 + 512 + 512
#define KSPLIT_LEN 1792     // 3584 / 2
// QK scale with log2(e) folded in: softmax uses exp2
#define QK_SCALE_L2E 0.12752462155f   // (1/sqrt(128)) * log2(e)

typedef unsigned short u16;
typedef short short8 __attribute__((ext_vector_type(8)));
typedef float f32x4 __attribute__((ext_vector_type(4)));

__device__ __forceinline__ u16 f2bf(float f) {
  union { float f; uint32_t u; } v; v.f = f;
  uint32_t r = v.u + 0x7fffu + ((v.u >> 16) & 1u);
  return (u16)(r >> 16);
}
__device__ __forceinline__ float bf2f(u16 u) {
  union { uint32_t u; float f; } v; v.u = ((uint32_t)u) << 16;
  return v.f;
}
__device__ __forceinline__ u16 nbf(float f) {  // native 1-op RNE cvt
  __hip_bfloat16 h = __float2bfloat16(f);
  return *reinterpret_cast<u16*>(&h);
}

#define GLL16(gp, lp) __builtin_amdgcn_global_load_lds( \
    (const __attribute__((address_space(1))) void*)(gp), \
    (__attribute__((address_space(3))) void*)(lp), 16, 0, 0)

// ---------------- f32 -> bf16 bulk convert (all 5 buffers, one launch) -------
__global__ __launch_bounds__(256) void cvt_all_kernel(
    const float* __restrict__ h, const float* __restrict__ qw,
    const float* __restrict__ kw, const float* __restrict__ vw,
    const float* __restrict__ ow,
    u16* __restrict__ hb, u16* __restrict__ qwb, u16* __restrict__ kwb,
    u16* __restrict__ vwb, u16* __restrict__ owb)
{
  const float* src; u16* dst; int n4;
  switch (blockIdx.y) {
    case 0: src = h;  dst = hb;  n4 = S_LEN * HID / 4; break;
    case 1: src = qw; dst = qwb; n4 = HID * HID / 4;   break;
    case 2: src = kw; dst = kwb; n4 = KVD * HID / 4;   break;
    case 3: src = vw; dst = vwb; n4 = KVD * HID / 4;   break;
    default: src = ow; dst = owb; n4 = HID * HID / 4;  break;
  }
  int i = blockIdx.x * blockDim.x + threadIdx.x;
  const int stride = gridDim.x * blockDim.x;
  for (; i < n4; i += stride) {
    float4 v = reinterpret_cast<const float4*>(src)[i];
    uint2 o;
    o.x = (uint32_t)f2bf(v.x) | ((uint32_t)f2bf(v.y) << 16);
    o.y = (uint32_t)f2bf(v.z) | ((uint32_t)f2bf(v.w) << 16);
    reinterpret_cast<uint2*>(dst)[i] = o;
  }
}

// ---- GEMM core: 128x256 tile, 8 waves (2Mx4N, wave=64x64), BK=32,
// triple-buffered LDS (24KB/buf -> 72KB total -> 2 blocks/CU), counted
// vmcnt (3 loads/thread/tile in flight; vmcnt(0) only at tail).
// Rows are 64B (4 x 16B chunks): double-XOR swizzle chunk ^= (r&3)^((r>>2)&3)
// keeps every consecutive-8-lane group on 8 distinct bank regions.
__device__ __forceinline__ void gemm_core_128x256_bk32(
    u16* lds, const u16* __restrict__ A, const u16* __restrict__ W,
    u16* __restrict__ C, int ldC, int lda, int T)
{
  const int t  = threadIdx.x;       // 0..511
  const int l  = t & 63;
  const int w  = t >> 6;            // 0..7
  const int lr = l & 15;
  const int lg = l >> 4;
  const int wm = (w >> 2) << 6;     // 0 or 64
  const int wn = (w & 3) << 6;      // 0,64,128,192
  const int sw = (((lr & 3) ^ ((lr >> 2) & 3)) << 3);

  const f32x4 fz = {0.f, 0.f, 0.f, 0.f};
  f32x4 acc[4][4];
#pragma unroll
  for (int i = 0; i < 4; ++i)
#pragma unroll
    for (int j = 0; j < 4; ++j) acc[i][j] = fz;

#define SWZC(e) ((e & 31) ^ ((((e >> 5) & 3) ^ ((e >> 7) & 3)) << 3))
#define STAGE3(kt, buf) do {                                          \
    { const int e_ = t * 8;                                           \
      const int r_ = e_ >> 5;  const int c_ = SWZC(e_);               \
      GLL16(A + (size_t)(kt) * 32 + (size_t)r_ * lda + c_, (buf) + e_); } \
    _Pragma("unroll")                                                 \
    for (int i_ = 0; i_ < 2; ++i_) {                                  \
      const int e_ = (i_ * 512 + t) * 8;                              \
      const int r_ = e_ >> 5;  const int c_ = SWZC(e_);               \
      GLL16(W + (size_t)(kt) * 32 + (size_t)r_ * lda + c_, (buf) + 4096 + e_); } \
  } while (0)

  STAGE3(0, lds);
  STAGE3(1, lds + 12288);

#pragma unroll 1
  for (int tk = 0; tk < T; ++tk) {
    if (tk + 1 < T) { asm volatile("s_waitcnt vmcnt(3)" ::: "memory"); }
    else            { asm volatile("s_waitcnt vmcnt(0)" ::: "memory"); }
    __builtin_amdgcn_sched_barrier(0);
    __builtin_amdgcn_s_barrier();
    __builtin_amdgcn_sched_barrier(0);

    if (tk + 2 < T) {
      u16* nb = lds + ((tk + 2) % 3) * 12288;
      STAGE3(tk + 2, nb);
    }

    const u16* As_ = lds + (tk % 3) * 12288;
    const u16* Bs_ = As_ + 4096;
    short8 af[4], bfr[4];
#pragma unroll
    for (int mi = 0; mi < 4; ++mi)
      af[mi] = *(const short8*)(As_ + (wm + mi * 16 + lr) * 32 + ((lg * 8) ^ sw));
#pragma unroll
    for (int ni = 0; ni < 4; ++ni)
      bfr[ni] = *(const short8*)(Bs_ + (wn + ni * 16 + lr) * 32 + ((lg * 8) ^ sw));
    __builtin_amdgcn_s_setprio(1);
#pragma unroll
    for (int mi = 0; mi < 4; ++mi)
#pragma unroll
      for (int ni = 0; ni < 4; ++ni)
        acc[mi][ni] = __builtin_amdgcn_mfma_f32_16x16x32_bf16(af[mi], bfr[ni], acc[mi][ni], 0, 0, 0);
    __builtin_amdgcn_s_setprio(0);
  }
#undef STAGE3
#undef SWZC

#pragma unroll
  for (int ni = 0; ni < 4; ++ni) {
    const int n = wn + ni * 16 + lr;
#pragma unroll
    for (int mi = 0; mi < 4; ++mi) {
#pragma unroll
      for (int r = 0; r < 4; ++r) {
        const int m = wm + mi * 16 + lg * 4 + r;
        C[(size_t)m * ldC + n] = f2bf(acc[mi][ni][r]);
      }
    }
  }
}

// QKV: partials [2][S][NQKV]; grid (16, 18, 2); XCD-chunk swizzle (288=8*36)
__global__ __launch_bounds__(512) void qkv_gemm_kernel(
    const u16* __restrict__ hb,
    const u16* __restrict__ qwb, const u16* __restrict__ kwb, const u16* __restrict__ vwb,
    u16* __restrict__ part)
{
  __shared__ u16 lds[3 * 12288];
  const int lin = blockIdx.y * 16 + blockIdx.x;   // 0..287, dispatch-linear
  const int swz = (lin & 7) * 36 + (lin >> 3);    // bijective XCD chunking
  const int m0  = (swz & 15) * 128;
  const int by  = swz >> 4;                       // 0..17
  const int k0  = blockIdx.z * KSPLIT_LEN;
  u16* Cz = part + (size_t)blockIdx.z * S_LEN * NQKV;
  const u16* Wp; size_t coff; int n0;
  if (by < 14)      { Wp = qwb; n0 = by * 256;        coff = n0; }
  else if (by < 16) { Wp = kwb; n0 = (by - 14) * 256; coff = HID + n0; }
  else              { Wp = vwb; n0 = (by - 16) * 256; coff = HID + KVD + n0; }
  gemm_core_128x256_bk32(lds, hb + (size_t)m0 * HID + k0,
                         Wp + (size_t)n0 * HID + k0,
                         Cz + (size_t)m0 * NQKV + coff, NQKV, HID, KSPLIT_LEN / 32);
}

// O-proj: partials [2][S][HID]; grid (16, 14, 2); XCD swizzle (224=8*28)
__global__ __launch_bounds__(512) void oproj_gemm_kernel(
    const u16* __restrict__ ao, const u16* __restrict__ owb, u16* __restrict__ part)
{
  __shared__ u16 lds[3 * 12288];
  const int lin = blockIdx.y * 16 + blockIdx.x;   // 0..223
  const int swz = (lin & 7) * 28 + (lin >> 3);
  const int m0  = (swz & 15) * 128;
  const int n0  = (swz >> 4) * 256;
  const int k0  = blockIdx.z * KSPLIT_LEN;
  u16* Cz = part + (size_t)blockIdx.z * S_LEN * HID;
  gemm_core_128x256_bk32(lds, ao + (size_t)m0 * HID + k0,
                         owb + (size_t)n0 * HID + k0,
                         Cz + (size_t)m0 * HID + n0, HID, HID, KSPLIT_LEN / 32);
}

// ------- QKV reduce: partial sum + bias + RoPE(+scale) + V-transpose -------
__global__ __launch_bounds__(256) void qkv_reduce_kernel(
    const u16* __restrict__ part,
    const float* __restrict__ q_b, const float* __restrict__ k_b,
    const float* __restrict__ v_b,
    const float* __restrict__ cosb, const float* __restrict__ sinb,
    u16* __restrict__ qbuf, u16* __restrict__ kbuf, u16* __restrict__ vtb)
{
  const int s   = blockIdx.y;
  const int c   = blockIdx.x * 256 + threadIdx.x;   // 0..2303
  const int seg = c >> 6;
  const int d   = c & 63;
  const u16* p0 = part + (size_t)s * NQKV;
  const u16* p1 = p0 + (size_t)S_LEN * NQKV;

  if (seg < 28) {
    const int base = seg * 128;
    const float lo = bf2f(p0[base + d])      + bf2f(p1[base + d])      + q_b[base + d];
    const float hi = bf2f(p0[base + d + 64]) + bf2f(p1[base + d + 64]) + q_b[base + d + 64];
    const float cc = cosb[s * HD + d];
    const float ss = sinb[s * HD + d];
    qbuf[(size_t)s * HID + base + d]      = f2bf((lo * cc - hi * ss) * QK_SCALE_L2E);
    qbuf[(size_t)s * HID + base + d + 64] = f2bf((lo * ss + hi * cc) * QK_SCALE_L2E);
  } else if (seg < 32) {
    const int hh = seg - 28;
    const int base = HID + hh * 128;
    const int bb = hh * 128;
    const float lo = bf2f(p0[base + d])      + bf2f(p1[base + d])      + k_b[bb + d];
    const float hi = bf2f(p0[base + d + 64]) + bf2f(p1[base + d + 64]) + k_b[bb + d + 64];
    const float cc = cosb[s * HD + d];
    const float ss = sinb[s * HD + d];
    kbuf[(size_t)s * KVD + bb + d]      = f2bf(lo * cc - hi * ss);
    kbuf[(size_t)s * KVD + bb + d + 64] = f2bf(lo * ss + hi * cc);
  } else {
    const int hh = seg - 32;
    const int base = HID + KVD + hh * 128;
    const int bb = hh * 128;
    const float lo = bf2f(p0[base + d])      + bf2f(p1[base + d])      + v_b[bb + d];
    const float hi = bf2f(p0[base + d + 64]) + bf2f(p1[base + d + 64]) + v_b[bb + d + 64];
    vtb[(size_t)(bb + d) * S_LEN + s]      = f2bf(lo);
    vtb[(size_t)(bb + d + 64) * S_LEN + s] = f2bf(hi);
  }
}

// ------- O-proj reduce: f32 out = p0 + p1 -------
__global__ __launch_bounds__(256) void o_reduce_kernel(
    const u16* __restrict__ part, float* __restrict__ out)
{
  const int i = blockIdx.x * 256 + threadIdx.x;   // 4 elems each
  const uint2 a = ((const uint2*)part)[i];
  const uint2 b = ((const uint2*)(part + (size_t)S_LEN * HID))[i];
  float4 o;
  o.x = bf2f((u16)(a.x & 0xffff)) + bf2f((u16)(b.x & 0xffff));
  o.y = bf2f((u16)(a.x >> 16))    + bf2f((u16)(b.x >> 16));
  o.z = bf2f((u16)(a.y & 0xffff)) + bf2f((u16)(b.y & 0xffff));
  o.w = bf2f((u16)(a.y >> 16))    + bf2f((u16)(b.y >> 16));
  ((float4*)out)[i] = o;
}

// ---------------- Flash attention (causal, GQA) ----------------
// PROVEN R6 structure (best measured ~90us): 256 thr, 4 waves x 16 q-rows,
// paired lo/hi tiles (33 uniform KV iters), double-buffered K/V with
// prefetch-before-compute, one barrier/iter, T13 defer-max, ones-MFMA
// row-sum, native cvt. Restored verbatim; do not touch.
__global__ __launch_bounds__(256) void attn_kernel(
    const u16* __restrict__ qb, const u16* __restrict__ kb,
    const u16* __restrict__ vtb, u16* __restrict__ ao)
{
  __shared__ u16 Ks[2][64 * 128];   // [kv][d], swizzled
  __shared__ u16 Vts[2][128 * 64];  // [d][kv], swizzled
  __shared__ u16 Ps[4][16 * 64];    // per-wave P, swizzled

  const int h   = blockIdx.y;
  const int kvh = h / REP;
  const int lo  = blockIdx.x;       // 0..15
  const int hi  = 31 - lo;
  const int t   = threadIdx.x;
  const int w   = t >> 6;
  const int l   = t & 63;
  const int lr  = l & 15;
  const int lg  = l >> 4;
  const int sw  = (lr & 7) << 3;
  const f32x4 fz = {0.f, 0.f, 0.f, 0.f};
  short8 onesv;
#pragma unroll
  for (int i = 0; i < 8; ++i) onesv[i] = (short)0x3F80;  // bf16 1.0

  const u16* kbh  = kb + kvh * HD;
  const u16* vtbh = vtb + (size_t)kvh * HD * S_LEN;

  int tile = lo;
  short8 qf[4];
  {
    const u16* qrow = qb + (size_t)(tile * 64 + w * 16 + lr) * HID + h * HD;
#pragma unroll
    for (int dk = 0; dk < 4; ++dk)
      qf[dk] = *(const short8*)(qrow + dk * 32 + lg * 8);
  }

  float m_r[4];
  f32x4 lacc;       // row-sum accumulator via ones-MFMA
  f32x4 o_acc[8];
#pragma unroll
  for (int r = 0; r < 4; ++r) m_r[r] = -1e30f;
  lacc = fz;
#pragma unroll
  for (int db = 0; db < 8; ++db) o_acc[db] = fz;

  // ---- prologue: stage kv tile 0 into buf 0 ----
#pragma unroll
  for (int i = 0; i < 4; ++i) {
    const int e  = (i * 256 + t) * 8;
    const int rk = e >> 7;
    const int ck = (e & 127) ^ ((rk & 7) << 3);
    GLL16(kbh + (size_t)rk * KVD + ck, &Ks[0][0] + e);
    const int rv = e >> 6;
    const int cv = (e & 63) ^ ((rv & 7) << 3);
    GLL16(vtbh + (size_t)rv * S_LEN + cv, &Vts[0][0] + e);
  }
  __syncthreads();

#pragma unroll 1
  for (int j = 0; j < 33; ++j) {
    const int buf = j & 1;
    // ---- issue prefetch of next kv tile into buf^1 ----
    if (j + 1 < 33) {
      const int jn  = j + 1;
      const int kvn = ((jn <= lo) ? jn : (jn - lo - 1)) * 64;
#pragma unroll
      for (int i = 0; i < 4; ++i) {
        const int e  = (i * 256 + t) * 8;
        const int rk = e >> 7;
        const int ck = (e & 127) ^ ((rk & 7) << 3);
        GLL16(kbh + (size_t)(kvn + rk) * KVD + ck, &Ks[buf ^ 1][0] + e);
        const int rv = e >> 6;
        const int cv = (e & 63) ^ ((rv & 7) << 3);
        GLL16(vtbh + (size_t)rv * S_LEN + kvn + cv, &Vts[buf ^ 1][0] + e);
      }
    }

    const int kv0 = ((j <= lo) ? j : (j - lo - 1)) * 64;
    const u16* ks = &Ks[buf][0];
    const u16* vs = &Vts[buf][0];

    // ---- QK^T : S[16 q x 64 kv] per wave ----
    f32x4 sacc[4];
#pragma unroll
    for (int kvt = 0; kvt < 4; ++kvt) sacc[kvt] = fz;
    __builtin_amdgcn_s_setprio(1);
#pragma unroll
    for (int kvt = 0; kvt < 4; ++kvt) {
#pragma unroll
      for (int dk = 0; dk < 4; ++dk) {
        const short8 kf = *(const short8*)(ks + (kvt * 16 + lr) * 128 + ((dk * 32 + lg * 8) ^ sw));
        sacc[kvt] = __builtin_amdgcn_mfma_f32_16x16x32_bf16(qf[dk], kf, sacc[kvt], 0, 0, 0);
      }
    }
    __builtin_amdgcn_s_setprio(0);

    const bool last_of_half = (j == lo) || (j == 32);
    if (last_of_half) {  // diagonal tile: causal mask
      const int q0w = tile * 64 + w * 16;
#pragma unroll
      for (int kvt = 0; kvt < 4; ++kvt) {
        const int col = kv0 + kvt * 16 + lr;
#pragma unroll
        for (int r = 0; r < 4; ++r) {
          if (col > q0w + lg * 4 + r) sacc[kvt][r] = -1e30f;
        }
      }
    }

    // ---- online softmax: max-reduce + defer-max (THR=8) ----
    float tmr[4];
    bool ok = true;
#pragma unroll
    for (int r = 0; r < 4; ++r) {
      float tm = fmaxf(fmaxf(sacc[0][r], sacc[1][r]), fmaxf(sacc[2][r], sacc[3][r]));
      tm = fmaxf(tm, __shfl_xor(tm, 1));
      tm = fmaxf(tm, __shfl_xor(tm, 2));
      tm = fmaxf(tm, __shfl_xor(tm, 4));
      tm = fmaxf(tm, __shfl_xor(tm, 8));
      tmr[r] = tm;
      ok = ok && (tm <= m_r[r] + 8.f);
    }
    if (!__all(ok)) {
#pragma unroll
      for (int r = 0; r < 4; ++r) {
        const float mn = fmaxf(m_r[r], tmr[r]);
        const float alpha = exp2f(m_r[r] - mn);
        m_r[r] = mn;
        lacc[r] *= alpha;
#pragma unroll
        for (int db = 0; db < 8; ++db) o_acc[db][r] *= alpha;
      }
    }

    // ---- P = exp2(S - m) -> per-wave LDS (bf16, swizzled) ----
#pragma unroll
    for (int kvt = 0; kvt < 4; ++kvt) {
#pragma unroll
      for (int r = 0; r < 4; ++r) {
        const int prow = lg * 4 + r;
        Ps[w][prow * 64 + ((kvt * 16 + lr) ^ ((prow & 7) << 3))] =
            nbf(exp2f(sacc[kvt][r] - m_r[r]));
      }
    }

    short8 pf[2];
#pragma unroll
    for (int ks2 = 0; ks2 < 2; ++ks2)
      pf[ks2] = *(const short8*)(&Ps[w][0] + lr * 64 + ((ks2 * 32 + lg * 8) ^ sw));

    // ---- PV (+ ones-column MFMA row-sum) ----
    __builtin_amdgcn_s_setprio(1);
    lacc = __builtin_amdgcn_mfma_f32_16x16x32_bf16(pf[0], onesv, lacc, 0, 0, 0);
    lacc = __builtin_amdgcn_mfma_f32_16x16x32_bf16(pf[1], onesv, lacc, 0, 0, 0);
#pragma unroll
    for (int db = 0; db < 8; ++db) {
#pragma unroll
      for (int ks2 = 0; ks2 < 2; ++ks2) {
        const short8 vf = *(const short8*)(vs + (db * 16 + lr) * 64 + ((ks2 * 32 + lg * 8) ^ sw));
        o_acc[db] = __builtin_amdgcn_mfma_f32_16x16x32_bf16(pf[ks2], vf, o_acc[db], 0, 0, 0);
      }
    }
    __builtin_amdgcn_s_setprio(0);

    // ---- end-of-half: epilogue + switch to hi tile ----
    if (last_of_half) {
#pragma unroll
      for (int r = 0; r < 4; ++r) {
        const float inv = 1.0f / lacc[r];
        u16* orow = ao + (size_t)(tile * 64 + w * 16 + lg * 4 + r) * HID + h * HD;
#pragma unroll
        for (int db = 0; db < 8; ++db)
          orow[db * 16 + lr] = nbf(o_acc[db][r] * inv);
      }
      if (j != 32) {
        tile = hi;
        const u16* qrow = qb + (size_t)(tile * 64 + w * 16 + lr) * HID + h * HD;
#pragma unroll
        for (int dk = 0; dk < 4; ++dk)
          qf[dk] = *(const short8*)(qrow + dk * 32 + lg * 8);
#pragma unroll
        for (int r = 0; r < 4; ++r) m_r[r] = -1e30f;
        lacc = fz;
#pragma unroll
        for (int db = 0; db < 8; ++db) o_acc[db] = fz;
      }
    }
    __syncthreads();  // drains prefetch + guards buf reuse
  }
}

// ---------------- launch ----------------
extern "C" void kernel_launch(void* const* d_in, const int* in_sizes, int n_in,
                              void* d_out, int out_size, void* d_ws, size_t ws_size,
                              hipStream_t stream) {
  const float* hidden = (const float*)d_in[0];
  const float* cosb = (const float*)d_in[2];
  const float* sinb = (const float*)d_in[3];
  const float* q_w  = (const float*)d_in[4];
  const float* q_b  = (const float*)d_in[5];
  const float* k_w  = (const float*)d_in[6];
  const float* k_b  = (const float*)d_in[7];
  const float* v_w  = (const float*)d_in[8];
  const float* v_b  = (const float*)d_in[9];
  const float* o_w  = (const float*)d_in[10];
  float* out = (float*)d_out;

  char* p = (char*)d_ws;
  u16* hb   = (u16*)p; p += (size_t)S_LEN * HID * 2;
  u16* qwb  = (u16*)p; p += (size_t)HID * HID * 2;
  u16* kwb  = (u16*)p; p += (size_t)KVD * HID * 2;
  u16* vwb  = (u16*)p; p += (size_t)KVD * HID * 2;
  u16* owb  = (u16*)p; p += (size_t)HID * HID * 2;
  u16* qbuf = (u16*)p; p += (size_t)S_LEN * HID * 2;
  u16* kbuf = (u16*)p; p += (size_t)S_LEN * KVD * 2;
  u16* vtb  = (u16*)p; p += (size_t)KVD * S_LEN * 2;
  u16* ao   = (u16*)p; p += (size_t)S_LEN * HID * 2;
  u16* part = (u16*)p; p += (size_t)2 * S_LEN * NQKV * 2;  // shared qkv/oproj partials
  if ((size_t)(p - (char*)d_ws) > ws_size) return;

  cvt_all_kernel<<<dim3(1024, 5), 256, 0, stream>>>(
      hidden, q_w, k_w, v_w, o_w, hb, qwb, kwb, vwb, owb);

  qkv_gemm_kernel<<<dim3(16, 18, 2), 512, 0, stream>>>(hb, qwb, kwb, vwb, part);
  qkv_reduce_kernel<<<dim3(9, S_LEN), 256, 0, stream>>>(
      part, q_b, k_b, v_b, cosb, sinb, qbuf, kbuf, vtb);

  attn_kernel<<<dim3(16, 28), 256, 0, stream>>>(qbuf, kbuf, vtb, ao);

  oproj_gemm_kernel<<<dim3(16, 14, 2), 512, 0, stream>>>(ao, owb, part);
  o_reduce_kernel<<<(S_LEN * HID / 4) / 256, 256, 0, stream>>>(part, out);
}

// Round 12
// 286.733 us; speedup vs baseline: 1.1554x; 1.0333x over previous
//
#include <hip/hip_runtime.h>
#include <hip/hip_bf16.h>
#include <stdint.h>
#include <stddef.h>

#define S_LEN 2048
#define HID   3584
#define NH    28
#define NKV   4
#define HD    128
#define REP   7
#define KVD   512
#define NQKV  4608          // 3584 + 512 + 512
#define KSPLIT_LEN 1792     // 3584 / 2
// QK scale with log2(e) folded in: softmax uses exp2
#define QK_SCALE_L2E 0.12752462155f   // (1/sqrt(128)) * log2(e)

typedef unsigned short u16;
typedef short short8 __attribute__((ext_vector_type(8)));
typedef float f32x4 __attribute__((ext_vector_type(4)));

__device__ __forceinline__ u16 f2bf(float f) {
  union { float f; uint32_t u; } v; v.f = f;
  uint32_t r = v.u + 0x7fffu + ((v.u >> 16) & 1u);
  return (u16)(r >> 16);
}
__device__ __forceinline__ float bf2f(u16 u) {
  union { uint32_t u; float f; } v; v.u = ((uint32_t)u) << 16;
  return v.f;
}
__device__ __forceinline__ u16 nbf(float f) {  // native 1-op RNE cvt
  __hip_bfloat16 h = __float2bfloat16(f);
  return *reinterpret_cast<u16*>(&h);
}

#define GLL16(gp, lp) __builtin_amdgcn_global_load_lds( \
    (const __attribute__((address_space(1))) void*)(gp), \
    (__attribute__((address_space(3))) void*)(lp), 16, 0, 0)

// ---------------- f32 -> bf16 bulk convert (all 5 buffers, one launch) -------
__global__ __launch_bounds__(256) void cvt_all_kernel(
    const float* __restrict__ h, const float* __restrict__ qw,
    const float* __restrict__ kw, const float* __restrict__ vw,
    const float* __restrict__ ow,
    u16* __restrict__ hb, u16* __restrict__ qwb, u16* __restrict__ kwb,
    u16* __restrict__ vwb, u16* __restrict__ owb)
{
  const float* src; u16* dst; int n4;
  switch (blockIdx.y) {
    case 0: src = h;  dst = hb;  n4 = S_LEN * HID / 4; break;
    case 1: src = qw; dst = qwb; n4 = HID * HID / 4;   break;
    case 2: src = kw; dst = kwb; n4 = KVD * HID / 4;   break;
    case 3: src = vw; dst = vwb; n4 = KVD * HID / 4;   break;
    default: src = ow; dst = owb; n4 = HID * HID / 4;  break;
  }
  int i = blockIdx.x * blockDim.x + threadIdx.x;
  const int stride = gridDim.x * blockDim.x;
  for (; i < n4; i += stride) {
    float4 v = reinterpret_cast<const float4*>(src)[i];
    uint2 o;
    o.x = (uint32_t)f2bf(v.x) | ((uint32_t)f2bf(v.y) << 16);
    o.y = (uint32_t)f2bf(v.z) | ((uint32_t)f2bf(v.w) << 16);
    reinterpret_cast<uint2*>(dst)[i] = o;
  }
}

// ---- GEMM core: 128x256 tile, 8 waves (2Mx4N, wave=64x64), BK=32,
// triple-buffered LDS (24KB/buf -> 72KB total -> 2 blocks/CU), counted
// vmcnt (3 loads/thread/tile in flight; vmcnt(0) only at tail).
__device__ __forceinline__ void gemm_core_128x256_bk32(
    u16* lds, const u16* __restrict__ A, const u16* __restrict__ W,
    u16* __restrict__ C, int ldC, int lda, int T)
{
  const int t  = threadIdx.x;       // 0..511
  const int l  = t & 63;
  const int w  = t >> 6;            // 0..7
  const int lr = l & 15;
  const int lg = l >> 4;
  const int wm = (w >> 2) << 6;     // 0 or 64
  const int wn = (w & 3) << 6;      // 0,64,128,192
  const int sw = (((lr & 3) ^ ((lr >> 2) & 3)) << 3);

  const f32x4 fz = {0.f, 0.f, 0.f, 0.f};
  f32x4 acc[4][4];
#pragma unroll
  for (int i = 0; i < 4; ++i)
#pragma unroll
    for (int j = 0; j < 4; ++j) acc[i][j] = fz;

#define SWZC(e) ((e & 31) ^ ((((e >> 5) & 3) ^ ((e >> 7) & 3)) << 3))
#define STAGE3(kt, buf) do {                                          \
    { const int e_ = t * 8;                                           \
      const int r_ = e_ >> 5;  const int c_ = SWZC(e_);               \
      GLL16(A + (size_t)(kt) * 32 + (size_t)r_ * lda + c_, (buf) + e_); } \
    _Pragma("unroll")                                                 \
    for (int i_ = 0; i_ < 2; ++i_) {                                  \
      const int e_ = (i_ * 512 + t) * 8;                              \
      const int r_ = e_ >> 5;  const int c_ = SWZC(e_);               \
      GLL16(W + (size_t)(kt) * 32 + (size_t)r_ * lda + c_, (buf) + 4096 + e_); } \
  } while (0)

  STAGE3(0, lds);
  STAGE3(1, lds + 12288);

#pragma unroll 1
  for (int tk = 0; tk < T; ++tk) {
    if (tk + 1 < T) { asm volatile("s_waitcnt vmcnt(3)" ::: "memory"); }
    else            { asm volatile("s_waitcnt vmcnt(0)" ::: "memory"); }
    __builtin_amdgcn_sched_barrier(0);
    __builtin_amdgcn_s_barrier();
    __builtin_amdgcn_sched_barrier(0);

    if (tk + 2 < T) {
      u16* nb = lds + ((tk + 2) % 3) * 12288;
      STAGE3(tk + 2, nb);
    }

    const u16* As_ = lds + (tk % 3) * 12288;
    const u16* Bs_ = As_ + 4096;
    short8 af[4], bfr[4];
#pragma unroll
    for (int mi = 0; mi < 4; ++mi)
      af[mi] = *(const short8*)(As_ + (wm + mi * 16 + lr) * 32 + ((lg * 8) ^ sw));
#pragma unroll
    for (int ni = 0; ni < 4; ++ni)
      bfr[ni] = *(const short8*)(Bs_ + (wn + ni * 16 + lr) * 32 + ((lg * 8) ^ sw));
    __builtin_amdgcn_s_setprio(1);
#pragma unroll
    for (int mi = 0; mi < 4; ++mi)
#pragma unroll
      for (int ni = 0; ni < 4; ++ni)
        acc[mi][ni] = __builtin_amdgcn_mfma_f32_16x16x32_bf16(af[mi], bfr[ni], acc[mi][ni], 0, 0, 0);
    __builtin_amdgcn_s_setprio(0);
  }
#undef STAGE3
#undef SWZC

#pragma unroll
  for (int ni = 0; ni < 4; ++ni) {
    const int n = wn + ni * 16 + lr;
#pragma unroll
    for (int mi = 0; mi < 4; ++mi) {
#pragma unroll
      for (int r = 0; r < 4; ++r) {
        const int m = wm + mi * 16 + lg * 4 + r;
        C[(size_t)m * ldC + n] = f2bf(acc[mi][ni][r]);
      }
    }
  }
}

// QKV: partials [2][S][NQKV]; grid (16, 18, 2); XCD-chunk swizzle (288=8*36)
__global__ __launch_bounds__(512) void qkv_gemm_kernel(
    const u16* __restrict__ hb,
    const u16* __restrict__ qwb, const u16* __restrict__ kwb, const u16* __restrict__ vwb,
    u16* __restrict__ part)
{
  __shared__ u16 lds[3 * 12288];
  const int lin = blockIdx.y * 16 + blockIdx.x;   // 0..287, dispatch-linear
  const int swz = (lin & 7) * 36 + (lin >> 3);    // bijective XCD chunking
  const int m0  = (swz & 15) * 128;
  const int by  = swz >> 4;                       // 0..17
  const int k0  = blockIdx.z * KSPLIT_LEN;
  u16* Cz = part + (size_t)blockIdx.z * S_LEN * NQKV;
  const u16* Wp; size_t coff; int n0;
  if (by < 14)      { Wp = qwb; n0 = by * 256;        coff = n0; }
  else if (by < 16) { Wp = kwb; n0 = (by - 14) * 256; coff = HID + n0; }
  else              { Wp = vwb; n0 = (by - 16) * 256; coff = HID + KVD + n0; }
  gemm_core_128x256_bk32(lds, hb + (size_t)m0 * HID + k0,
                         Wp + (size_t)n0 * HID + k0,
                         Cz + (size_t)m0 * NQKV + coff, NQKV, HID, KSPLIT_LEN / 32);
}

// O-proj: partials [2][S][HID]; grid (16, 14, 2); XCD swizzle (224=8*28)
__global__ __launch_bounds__(512) void oproj_gemm_kernel(
    const u16* __restrict__ ao, const u16* __restrict__ owb, u16* __restrict__ part)
{
  __shared__ u16 lds[3 * 12288];
  const int lin = blockIdx.y * 16 + blockIdx.x;   // 0..223
  const int swz = (lin & 7) * 28 + (lin >> 3);
  const int m0  = (swz & 15) * 128;
  const int n0  = (swz >> 4) * 256;
  const int k0  = blockIdx.z * KSPLIT_LEN;
  u16* Cz = part + (size_t)blockIdx.z * S_LEN * HID;
  gemm_core_128x256_bk32(lds, ao + (size_t)m0 * HID + k0,
                         owb + (size_t)n0 * HID + k0,
                         Cz + (size_t)m0 * HID + n0, HID, HID, KSPLIT_LEN / 32);
}

// ------- QKV reduce: partial sum + bias + RoPE(+scale) + V-transpose -------
__global__ __launch_bounds__(256) void qkv_reduce_kernel(
    const u16* __restrict__ part,
    const float* __restrict__ q_b, const float* __restrict__ k_b,
    const float* __restrict__ v_b,
    const float* __restrict__ cosb, const float* __restrict__ sinb,
    u16* __restrict__ qbuf, u16* __restrict__ kbuf, u16* __restrict__ vtb)
{
  const int s   = blockIdx.y;
  const int c   = blockIdx.x * 256 + threadIdx.x;   // 0..2303
  const int seg = c >> 6;
  const int d   = c & 63;
  const u16* p0 = part + (size_t)s * NQKV;
  const u16* p1 = p0 + (size_t)S_LEN * NQKV;

  if (seg < 28) {
    const int base = seg * 128;
    const float lo = bf2f(p0[base + d])      + bf2f(p1[base + d])      + q_b[base + d];
    const float hi = bf2f(p0[base + d + 64]) + bf2f(p1[base + d + 64]) + q_b[base + d + 64];
    const float cc = cosb[s * HD + d];
    const float ss = sinb[s * HD + d];
    qbuf[(size_t)s * HID + base + d]      = f2bf((lo * cc - hi * ss) * QK_SCALE_L2E);
    qbuf[(size_t)s * HID + base + d + 64] = f2bf((lo * ss + hi * cc) * QK_SCALE_L2E);
  } else if (seg < 32) {
    const int hh = seg - 28;
    const int base = HID + hh * 128;
    const int bb = hh * 128;
    const float lo = bf2f(p0[base + d])      + bf2f(p1[base + d])      + k_b[bb + d];
    const float hi = bf2f(p0[base + d + 64]) + bf2f(p1[base + d + 64]) + k_b[bb + d + 64];
    const float cc = cosb[s * HD + d];
    const float ss = sinb[s * HD + d];
    kbuf[(size_t)s * KVD + bb + d]      = f2bf(lo * cc - hi * ss);
    kbuf[(size_t)s * KVD + bb + d + 64] = f2bf(lo * ss + hi * cc);
  } else {
    const int hh = seg - 32;
    const int base = HID + KVD + hh * 128;
    const int bb = hh * 128;
    const float lo = bf2f(p0[base + d])      + bf2f(p1[base + d])      + v_b[bb + d];
    const float hi = bf2f(p0[base + d + 64]) + bf2f(p1[base + d + 64]) + v_b[bb + d + 64];
    vtb[(size_t)(bb + d) * S_LEN + s]      = f2bf(lo);
    vtb[(size_t)(bb + d + 64) * S_LEN + s] = f2bf(hi);
  }
}

// ------- O-proj reduce: f32 out = p0 + p1 -------
__global__ __launch_bounds__(256) void o_reduce_kernel(
    const u16* __restrict__ part, float* __restrict__ out)
{
  const int i = blockIdx.x * 256 + threadIdx.x;   // 4 elems each
  const uint2 a = ((const uint2*)part)[i];
  const uint2 b = ((const uint2*)(part + (size_t)S_LEN * HID))[i];
  float4 o;
  o.x = bf2f((u16)(a.x & 0xffff)) + bf2f((u16)(b.x & 0xffff));
  o.y = bf2f((u16)(a.x >> 16))    + bf2f((u16)(b.x >> 16));
  o.z = bf2f((u16)(a.y & 0xffff)) + bf2f((u16)(b.y & 0xffff));
  o.w = bf2f((u16)(a.y >> 16))    + bf2f((u16)(b.y >> 16));
  ((float4*)out)[i] = o;
}

// ---------------- Flash attention (causal, GQA) ----------------
// R6 structure (proven best): 256 thr, 4 waves x 16 q-rows, paired lo/hi
// tiles (33 uniform KV iters), dbuf K/V prefetch-before-compute, ones-MFMA
// row-sum, native cvt. NEW: thread-local defer-max trigger — the 16-shfl
// max-reduce runs ONLY when some thread's local max exceeds m_r+8 (first
// iter + rare growth); steady state pays 3 fmax per row, no cross-lane ops.
__global__ __launch_bounds__(256) void attn_kernel(
    const u16* __restrict__ qb, const u16* __restrict__ kb,
    const u16* __restrict__ vtb, u16* __restrict__ ao)
{
  __shared__ u16 Ks[2][64 * 128];   // [kv][d], swizzled
  __shared__ u16 Vts[2][128 * 64];  // [d][kv], swizzled
  __shared__ u16 Ps[4][16 * 64];    // per-wave P, swizzled

  const int h   = blockIdx.y;
  const int kvh = h / REP;
  const int lo  = blockIdx.x;       // 0..15
  const int hi  = 31 - lo;
  const int t   = threadIdx.x;
  const int w   = t >> 6;
  const int l   = t & 63;
  const int lr  = l & 15;
  const int lg  = l >> 4;
  const int sw  = (lr & 7) << 3;
  const f32x4 fz = {0.f, 0.f, 0.f, 0.f};
  short8 onesv;
#pragma unroll
  for (int i = 0; i < 8; ++i) onesv[i] = (short)0x3F80;  // bf16 1.0

  const u16* kbh  = kb + kvh * HD;
  const u16* vtbh = vtb + (size_t)kvh * HD * S_LEN;

  int tile = lo;
  short8 qf[4];
  {
    const u16* qrow = qb + (size_t)(tile * 64 + w * 16 + lr) * HID + h * HD;
#pragma unroll
    for (int dk = 0; dk < 4; ++dk)
      qf[dk] = *(const short8*)(qrow + dk * 32 + lg * 8);
  }

  float m_r[4];
  f32x4 lacc;       // row-sum accumulator via ones-MFMA
  f32x4 o_acc[8];
#pragma unroll
  for (int r = 0; r < 4; ++r) m_r[r] = -1e30f;
  lacc = fz;
#pragma unroll
  for (int db = 0; db < 8; ++db) o_acc[db] = fz;

  // ---- prologue: stage kv tile 0 into buf 0 ----
#pragma unroll
  for (int i = 0; i < 4; ++i) {
    const int e  = (i * 256 + t) * 8;
    const int rk = e >> 7;
    const int ck = (e & 127) ^ ((rk & 7) << 3);
    GLL16(kbh + (size_t)rk * KVD + ck, &Ks[0][0] + e);
    const int rv = e >> 6;
    const int cv = (e & 63) ^ ((rv & 7) << 3);
    GLL16(vtbh + (size_t)rv * S_LEN + cv, &Vts[0][0] + e);
  }
  __syncthreads();

#pragma unroll 1
  for (int j = 0; j < 33; ++j) {
    const int buf = j & 1;
    // ---- issue prefetch of next kv tile into buf^1 ----
    if (j + 1 < 33) {
      const int jn  = j + 1;
      const int kvn = ((jn <= lo) ? jn : (jn - lo - 1)) * 64;
#pragma unroll
      for (int i = 0; i < 4; ++i) {
        const int e  = (i * 256 + t) * 8;
        const int rk = e >> 7;
        const int ck = (e & 127) ^ ((rk & 7) << 3);
        GLL16(kbh + (size_t)(kvn + rk) * KVD + ck, &Ks[buf ^ 1][0] + e);
        const int rv = e >> 6;
        const int cv = (e & 63) ^ ((rv & 7) << 3);
        GLL16(vtbh + (size_t)rv * S_LEN + kvn + cv, &Vts[buf ^ 1][0] + e);
      }
    }

    const int kv0 = ((j <= lo) ? j : (j - lo - 1)) * 64;
    const u16* ks = &Ks[buf][0];
    const u16* vs = &Vts[buf][0];

    // ---- QK^T : S[16 q x 64 kv] per wave ----
    f32x4 sacc[4];
#pragma unroll
    for (int kvt = 0; kvt < 4; ++kvt) sacc[kvt] = fz;
    __builtin_amdgcn_s_setprio(1);
#pragma unroll
    for (int kvt = 0; kvt < 4; ++kvt) {
#pragma unroll
      for (int dk = 0; dk < 4; ++dk) {
        const short8 kf = *(const short8*)(ks + (kvt * 16 + lr) * 128 + ((dk * 32 + lg * 8) ^ sw));
        sacc[kvt] = __builtin_amdgcn_mfma_f32_16x16x32_bf16(qf[dk], kf, sacc[kvt], 0, 0, 0);
      }
    }
    __builtin_amdgcn_s_setprio(0);

    const bool last_of_half = (j == lo) || (j == 32);
    if (last_of_half) {  // diagonal tile: causal mask
      const int q0w = tile * 64 + w * 16;
#pragma unroll
      for (int kvt = 0; kvt < 4; ++kvt) {
        const int col = kv0 + kvt * 16 + lr;
#pragma unroll
        for (int r = 0; r < 4; ++r) {
          if (col > q0w + lg * 4 + r) sacc[kvt][r] = -1e30f;
        }
      }
    }

    // ---- online softmax: THREAD-LOCAL defer-max trigger (THR=8) ----
    float lm[4];
    bool ok = true;
#pragma unroll
    for (int r = 0; r < 4; ++r) {
      lm[r] = fmaxf(fmaxf(sacc[0][r], sacc[1][r]), fmaxf(sacc[2][r], sacc[3][r]));
      ok = ok && (lm[r] <= m_r[r] + 8.f);
    }
    if (!__all(ok)) {   // rare: full cross-lane reduce + rescale
#pragma unroll
      for (int r = 0; r < 4; ++r) {
        float tm = lm[r];
        tm = fmaxf(tm, __shfl_xor(tm, 1));
        tm = fmaxf(tm, __shfl_xor(tm, 2));
        tm = fmaxf(tm, __shfl_xor(tm, 4));
        tm = fmaxf(tm, __shfl_xor(tm, 8));
        const float mn = fmaxf(m_r[r], tm);
        const float alpha = exp2f(m_r[r] - mn);
        m_r[r] = mn;
        lacc[r] *= alpha;
#pragma unroll
        for (int db = 0; db < 8; ++db) o_acc[db][r] *= alpha;
      }
    }

    // ---- P = exp2(S - m) -> per-wave LDS (bf16, swizzled) ----
#pragma unroll
    for (int kvt = 0; kvt < 4; ++kvt) {
#pragma unroll
      for (int r = 0; r < 4; ++r) {
        const int prow = lg * 4 + r;
        Ps[w][prow * 64 + ((kvt * 16 + lr) ^ ((prow & 7) << 3))] =
            nbf(exp2f(sacc[kvt][r] - m_r[r]));
      }
    }

    short8 pf[2];
#pragma unroll
    for (int ks2 = 0; ks2 < 2; ++ks2)
      pf[ks2] = *(const short8*)(&Ps[w][0] + lr * 64 + ((ks2 * 32 + lg * 8) ^ sw));

    // ---- PV (+ ones-column MFMA row-sum) ----
    __builtin_amdgcn_s_setprio(1);
    lacc = __builtin_amdgcn_mfma_f32_16x16x32_bf16(pf[0], onesv, lacc, 0, 0, 0);
    lacc = __builtin_amdgcn_mfma_f32_16x16x32_bf16(pf[1], onesv, lacc, 0, 0, 0);
#pragma unroll
    for (int db = 0; db < 8; ++db) {
#pragma unroll
      for (int ks2 = 0; ks2 < 2; ++ks2) {
        const short8 vf = *(const short8*)(vs + (db * 16 + lr) * 64 + ((ks2 * 32 + lg * 8) ^ sw));
        o_acc[db] = __builtin_amdgcn_mfma_f32_16x16x32_bf16(pf[ks2], vf, o_acc[db], 0, 0, 0);
      }
    }
    __builtin_amdgcn_s_setprio(0);

    // ---- end-of-half: epilogue + switch to hi tile ----
    if (last_of_half) {
#pragma unroll
      for (int r = 0; r < 4; ++r) {
        const float inv = 1.0f / lacc[r];
        u16* orow = ao + (size_t)(tile * 64 + w * 16 + lg * 4 + r) * HID + h * HD;
#pragma unroll
        for (int db = 0; db < 8; ++db)
          orow[db * 16 + lr] = nbf(o_acc[db][r] * inv);
      }
      if (j != 32) {
        tile = hi;
        const u16* qrow = qb + (size_t)(tile * 64 + w * 16 + lr) * HID + h * HD;
#pragma unroll
        for (int dk = 0; dk < 4; ++dk)
          qf[dk] = *(const short8*)(qrow + dk * 32 + lg * 8);
#pragma unroll
        for (int r = 0; r < 4; ++r) m_r[r] = -1e30f;
        lacc = fz;
#pragma unroll
        for (int db = 0; db < 8; ++db) o_acc[db] = fz;
      }
    }
    __syncthreads();  // drains prefetch + guards buf reuse
  }
}

// ---------------- launch ----------------
extern "C" void kernel_launch(void* const* d_in, const int* in_sizes, int n_in,
                              void* d_out, int out_size, void* d_ws, size_t ws_size,
                              hipStream_t stream) {
  const float* hidden = (const float*)d_in[0];
  const float* cosb = (const float*)d_in[2];
  const float* sinb = (const float*)d_in[3];
  const float* q_w  = (const float*)d_in[4];
  const float* q_b  = (const float*)d_in[5];
  const float* k_w  = (const float*)d_in[6];
  const float* k_b  = (const float*)d_in[7];
  const float* v_w  = (const float*)d_in[8];
  const float* v_b  = (const float*)d_in[9];
  const float* o_w  = (const float*)d_in[10];
  float* out = (float*)d_out;

  char* p = (char*)d_ws;
  u16* hb   = (u16*)p; p += (size_t)S_LEN * HID * 2;
  u16* qwb  = (u16*)p; p += (size_t)HID * HID * 2;
  u16* kwb  = (u16*)p; p += (size_t)KVD * HID * 2;
  u16* vwb  = (u16*)p; p += (size_t)KVD * HID * 2;
  u16* owb  = (u16*)p; p += (size_t)HID * HID * 2;
  u16* qbuf = (u16*)p; p += (size_t)S_LEN * HID * 2;
  u16* kbuf = (u16*)p; p += (size_t)S_LEN * KVD * 2;
  u16* vtb  = (u16*)p; p += (size_t)KVD * S_LEN * 2;
  u16* ao   = (u16*)p; p += (size_t)S_LEN * HID * 2;
  u16* part = (u16*)p; p += (size_t)2 * S_LEN * NQKV * 2;  // shared qkv/oproj partials
  if ((size_t)(p - (char*)d_ws) > ws_size) return;

  cvt_all_kernel<<<dim3(1024, 5), 256, 0, stream>>>(
      hidden, q_w, k_w, v_w, o_w, hb, qwb, kwb, vwb, owb);

  qkv_gemm_kernel<<<dim3(16, 18, 2), 512, 0, stream>>>(hb, qwb, kwb, vwb, part);
  qkv_reduce_kernel<<<dim3(9, S_LEN), 256, 0, stream>>>(
      part, q_b, k_b, v_b, cosb, sinb, qbuf, kbuf, vtb);

  attn_kernel<<<dim3(16, 28), 256, 0, stream>>>(qbuf, kbuf, vtb, ao);

  oproj_gemm_kernel<<<dim3(16, 14, 2), 512, 0, stream>>>(ao, owb, part);
  o_reduce_kernel<<<(S_LEN * HID / 4) / 256, 256, 0, stream>>>(part, out);
}